// Round 2
// baseline (1072.436 us; speedup 1.0000x reference)
//
#include <hip/hip_runtime.h>
#include <hip/hip_bf16.h>

#define NB 8
#define NM 20000
#define NR 50000
#define NE 100000
#define BN_EPS 1e-5f

typedef unsigned int u32;

struct alignas(16) BF16x8 { __hip_bfloat16 v[8]; };

__device__ inline void store8v(__hip_bfloat16* p, const float* v) {
    BF16x8 pk;
#pragma unroll
    for (int j = 0; j < 8; ++j) pk.v[j] = __float2bfloat16(v[j]);
    *(BF16x8*)p = pk;
}
__device__ inline void store8v(float* p, const float* v) {
    *(float4*)p = make_float4(v[0], v[1], v[2], v[3]);
    *(float4*)(p + 4) = make_float4(v[4], v[5], v[6], v[7]);
}

// ---------------------------------------------------------------------------
// CSR build: histogram, 4-list scan, fill
// ---------------------------------------------------------------------------
__global__ __launch_bounds__(256) void hist_k(const int* __restrict__ dst,
                                              int* __restrict__ cnt, int n) {
    int i = blockIdx.x * 256 + threadIdx.x;
    if (i < n) atomicAdd(&cnt[dst[i]], 1);
}

// off[0]=0 ; off[i+1]=cumsum(cnt[0..i]); one block per list
__global__ __launch_bounds__(1024) void scan4_k(
    const int* c0, int* o0, int n0, const int* c1, int* o1, int n1,
    const int* c2, int* o2, int n2, const int* c3, int* o3, int n3) {
    const int* c; int* o; int n;
    if (blockIdx.x == 0) { c = c0; o = o0; n = n0; }
    else if (blockIdx.x == 1) { c = c1; o = o1; n = n1; }
    else if (blockIdx.x == 2) { c = c2; o = o2; n = n2; }
    else { c = c3; o = o3; n = n3; }
    __shared__ int wsum[16];
    __shared__ int carry_s;
    int t = threadIdx.x, lane = t & 63, w = t >> 6;
    if (t == 0) carry_s = 0;
    __syncthreads();
    for (int base = 0; base < n; base += 1024) {
        int i = base + t;
        int x = (i < n) ? c[i] : 0;
#pragma unroll
        for (int s = 1; s < 64; s <<= 1) {
            int y = __shfl_up(x, s);
            if (lane >= s) x += y;
        }
        if (lane == 63) wsum[w] = x;
        __syncthreads();
        if (w == 0) {
            int ws = (lane < 16) ? wsum[lane] : 0;
#pragma unroll
            for (int s = 1; s < 16; s <<= 1) {
                int y = __shfl_up(ws, s);
                if (lane >= s) ws += y;
            }
            if (lane < 16) wsum[lane] = ws;  // inclusive over waves
        }
        __syncthreads();
        int wbase = (w > 0) ? wsum[w - 1] : 0;
        int incl = x + wbase + carry_s;
        if (i < n) o[i + 1] = incl;
        __syncthreads();
        if (t == 1023) carry_s = incl;
        __syncthreads();
    }
    if (t == 0) o[0] = 0;
}

__global__ __launch_bounds__(256) void fill_k(const int* __restrict__ edges,
                                              const int* __restrict__ off,
                                              int* __restrict__ cur,
                                              int* __restrict__ idx, int n) {
    int i = blockIdx.x * 256 + threadIdx.x;
    if (i < n) {
        int d = edges[n + i];  // dst at [E,2E)
        int p = atomicAdd(&cur[d], 1);
        idx[off[d] + p] = edges[i];  // src
    }
}

// ---------------------------------------------------------------------------
// weight preps
// ---------------------------------------------------------------------------
__global__ __launch_bounds__(128) void transpose_k(const float* __restrict__ w,
                                                   float* __restrict__ wt) {
    int k = blockIdx.x, h = threadIdx.x;
    wt[k * 128 + h] = w[h * 128 + k];
}

// Wt1[k][h] = w_ra1[h][k&127] (duplicated halves); bias1 = [b_ra1 | w_ra1@b_rct | w_ra1@b_prd]
__global__ __launch_bounds__(128) void prep_w1_k(const float* __restrict__ w_ra1,
                                                 const float* __restrict__ b_ra1,
                                                 const float* __restrict__ b_rct,
                                                 const float* __restrict__ b_prd,
                                                 float* __restrict__ Wt1,
                                                 float* __restrict__ bias1) {
    int k = blockIdx.x, h = threadIdx.x;
    Wt1[k * 128 + h] = w_ra1[h * 128 + (k & 127)];
    if (k == 0) {
        float s1 = 0.f, s2 = 0.f;
        for (int j = 0; j < 128; ++j) {
            float w = w_ra1[h * 128 + j];
            s1 = fmaf(w, b_rct[j], s1);
            s2 = fmaf(w, b_prd[j], s2);
        }
        bias1[h] = b_ra1[h];
        bias1[128 + h] = s1;
        bias1[256 + h] = s2;
    }
}

// BN1 fold into w_ra2: W2p[j][d] = w_ra2[j][d]*s1[d]; b2p = w_ra2@t1 + b_ra2
__global__ __launch_bounds__(128) void prep2a_k(const float* __restrict__ ssum,
                                                const float* __restrict__ ssq,
                                                const float* __restrict__ g,
                                                const float* __restrict__ beta,
                                                const float* __restrict__ w_ra2,
                                                const float* __restrict__ b_ra2,
                                                float Nf, float* __restrict__ W2p,
                                                float* __restrict__ b2p) {
    int h = threadIdx.x;
    __shared__ float t1[128];
    float mean = ssum[h] / Nf;
    float var = ssq[h] / Nf - mean * mean;
    float sv = g[h] * rsqrtf(var + BN_EPS);
    t1[h] = beta[h] - mean * sv;
    for (int r = 0; r < 128; ++r) W2p[r * 128 + h] = w_ra2[r * 128 + h] * sv;
    __syncthreads();
    float sb = 0.f;
    for (int d = 0; d < 128; ++d) sb = fmaf(t1[d], w_ra2[h * 128 + d], sb);
    b2p[h] = sb + b_ra2[h];
}

// Wc = w_r2x @ W2p ; bc = w_r2x @ b2p + b_r2x
__global__ __launch_bounds__(128) void prep2b_k(const float* __restrict__ w_r2rct,
                                                const float* __restrict__ b_r2rct,
                                                const float* __restrict__ w_r2prd,
                                                const float* __restrict__ b_r2prd,
                                                const float* __restrict__ W2p,
                                                const float* __restrict__ b2p,
                                                float* __restrict__ Wc_r,
                                                float* __restrict__ bc_r,
                                                float* __restrict__ Wc_p,
                                                float* __restrict__ bc_p) {
    int blk = blockIdx.x;
    int d = threadIdx.x;
    int h = blk & 127;
    bool second = blk >= 128;
    const float* w = second ? w_r2prd : w_r2rct;
    const float* bsrc = second ? b_r2prd : b_r2rct;
    float* Wc = second ? Wc_p : Wc_r;
    float* bc = second ? bc_p : bc_r;
    __shared__ float rowv[128];
    __shared__ float red[128];
    rowv[d] = w[h * 128 + d];
    __syncthreads();
    float s = 0.f;
#pragma unroll 4
    for (int j = 0; j < 128; ++j) s = fmaf(rowv[j], W2p[j * 128 + d], s);
    Wc[h * 128 + d] = s;
    red[d] = rowv[d] * b2p[d];
    __syncthreads();
    for (int off = 64; off > 0; off >>= 1) {
        if (d < off) red[d] += red[d + off];
        __syncthreads();
    }
    if (d == 0) bc[h] = red[0] + bsrc[h];
}

// Wt[k][h] = (w_big @ w_src)[h][k&127] k-major; bias = [b_big | w_big@b_s1 | w_big@b_s2]
__global__ __launch_bounds__(128) void prep1_k(const float* __restrict__ w_s1,
                                               const float* __restrict__ w_s2,
                                               const float* __restrict__ w_big,
                                               const float* __restrict__ b_s1,
                                               const float* __restrict__ b_s2,
                                               const float* __restrict__ b_big,
                                               float* __restrict__ Wt,
                                               float* __restrict__ bias) {
    int k = blockIdx.x;
    int h = threadIdx.x;
    __shared__ float col[128];
    const float* wsrc = (k < 128) ? w_s1 : w_s2;
    int kk = k & 127;
    col[h] = wsrc[h * 128 + kk];
    __syncthreads();
    float s = 0.f;
#pragma unroll 4
    for (int j = 0; j < 128; ++j) s = fmaf(w_big[h * 128 + j], col[j], s);
    Wt[k * 128 + h] = s;
    if (k == 0) {
        float sb1 = 0.f, sb2 = 0.f;
        for (int j = 0; j < 128; ++j) {
            sb1 = fmaf(w_big[h * 128 + j], b_s1[j], sb1);
            sb2 = fmaf(w_big[h * 128 + j], b_s2[j], sb2);
        }
        bias[h] = b_big[h];
        bias[128 + h] = sb1;
        bias[256 + h] = sb2;
    }
}

// BN2 fold into w_ma2: WoutT[k][h] = w_ma2[h][k]*s2[k]; b_out = w_ma2@t2 + b_ma2
__global__ __launch_bounds__(128) void prep3_k(const float* __restrict__ ssum,
                                               const float* __restrict__ ssq,
                                               const float* __restrict__ g,
                                               const float* __restrict__ beta,
                                               const float* __restrict__ w_ma2,
                                               const float* __restrict__ b_ma2,
                                               float Nf, float* __restrict__ WoutT,
                                               float* __restrict__ b_out) {
    int h = threadIdx.x;
    __shared__ float s2[128], t2[128];
    float mean = ssum[h] / Nf;
    float var = ssq[h] / Nf - mean * mean;
    float sv = g[h] * rsqrtf(var + BN_EPS);
    s2[h] = sv;
    t2[h] = beta[h] - mean * sv;
    __syncthreads();
    for (int k = 0; k < 128; ++k) WoutT[k * 128 + h] = w_ma2[h * 128 + k] * s2[k];
    float sb = 0.f;
    for (int k = 0; k < 128; ++k) sb = fmaf(t2[k], w_ma2[h * 128 + k], sb);
    b_out[h] = sb + b_ma2[h];
}

// ---------------------------------------------------------------------------
// dense GEMM: Out[n, coloff + 0:128] = A[n,0:128] @ Wt(128x128 k-major) (+bias)
// 64-row x 128-col tile, 256 threads, thread tile 4x8
// ---------------------------------------------------------------------------
template <typename OT, bool BIAS>
__global__ __launch_bounds__(256) void gemm_dense(const float* __restrict__ A,
                                                  const float* __restrict__ Wt,
                                                  const float* __restrict__ bias,
                                                  OT* __restrict__ Out, int ldo,
                                                  int coloff) {
    __shared__ float Asm[64][36];
    __shared__ float Bsm[32][132];
    const int t = threadIdx.x;
    const int n0 = blockIdx.x * 64;
    const int tn = t & 15, tm = t >> 4;
    float acc[4][8];
#pragma unroll
    for (int i = 0; i < 4; ++i)
#pragma unroll
        for (int j = 0; j < 8; ++j) acc[i][j] = 0.f;

    for (int kt = 0; kt < 4; ++kt) {
#pragma unroll
        for (int it = 0; it < 16; ++it) {
            int id = t + 256 * it;
            int kk = id >> 7, h = id & 127;
            Bsm[kk][h] = Wt[(kt * 32 + kk) * 128 + h];
        }
#pragma unroll
        for (int it = 0; it < 8; ++it) {
            int id = t + 256 * it;
            int row = id >> 5, kk = id & 31;
            Asm[row][kk] = A[(size_t)(n0 + row) * 128 + kt * 32 + kk];
        }
        __syncthreads();
#pragma unroll
        for (int kk = 0; kk < 32; ++kk) {
            float av[4];
#pragma unroll
            for (int i = 0; i < 4; ++i) av[i] = Asm[tm * 4 + i][kk];
            const float4 b0 = *(const float4*)&Bsm[kk][tn * 8];
            const float4 b1 = *(const float4*)&Bsm[kk][tn * 8 + 4];
            float bv[8] = {b0.x, b0.y, b0.z, b0.w, b1.x, b1.y, b1.z, b1.w};
#pragma unroll
            for (int i = 0; i < 4; ++i)
#pragma unroll
                for (int j = 0; j < 8; ++j) acc[i][j] = fmaf(av[i], bv[j], acc[i][j]);
        }
        __syncthreads();
    }
    float bb[8];
#pragma unroll
    for (int j = 0; j < 8; ++j) bb[j] = BIAS ? bias[tn * 8 + j] : 0.f;
#pragma unroll
    for (int i = 0; i < 4; ++i) {
        float vals[8];
#pragma unroll
        for (int j = 0; j < 8; ++j) vals[j] = acc[i][j] + bb[j];
        store8v(&Out[(size_t)(n0 + tm * 4 + i) * ldo + coloff + tn * 8], vals);
    }
}

// ---------------------------------------------------------------------------
// gather GEMM: per output row n (b = n/nbins, r = n%nbins):
//   A1 = mean over CSR1[r] of src[b, idx, half1cols]   (128 k)
//   A2 = mean over CSR2[r] of src[b, idx, half2cols]   (128 k)
//   v = relu( [A1 A2] @ Wt(256x128) + base + m1*bm1 + m2*bm2 ) ; stats sum/sq
// ---------------------------------------------------------------------------
template <typename OT>
__global__ __launch_bounds__(256) void gemm_gather(
    const __hip_bfloat16* __restrict__ src, int srcw, int h2off, int nsrc, int nbins,
    const int* __restrict__ off1, const int* __restrict__ idx1,
    const int* __restrict__ off2, const int* __restrict__ idx2,
    const float* __restrict__ Wt, const float* __restrict__ biasv,
    OT* __restrict__ Out, float* __restrict__ ssum, float* __restrict__ ssq) {
    __shared__ float Asm[64][132];
    __shared__ float Bsm[32][132];
    __shared__ float m1s[64], m2s[64];
    const int t = threadIdx.x, n0 = blockIdx.x * 64;
    const int grow = t >> 2, gtc = t & 3;
    const int tn = t & 15, tm = t >> 4;
    const int n = n0 + grow;
    const int b = n / nbins;
    const int r = n - b * nbins;

    float acc[4][8];
#pragma unroll
    for (int i = 0; i < 4; ++i)
#pragma unroll
        for (int j = 0; j < 8; ++j) acc[i][j] = 0.f;

    for (int half = 0; half < 2; ++half) {
        const int* off = half ? off2 : off1;
        const int* idx = half ? idx2 : idx1;
        int e0 = off[r], e1 = off[r + 1];
        float g[32];
#pragma unroll
        for (int j = 0; j < 32; ++j) g[j] = 0.f;
        const __hip_bfloat16* base =
            src + (size_t)b * nsrc * srcw + (half ? h2off : 0) + gtc * 32;
        for (int e = e0; e < e1; ++e) {
            const __hip_bfloat16* p = base + (size_t)idx[e] * srcw;
#pragma unroll
            for (int q4 = 0; q4 < 4; ++q4) {
                uint4 qq = *(const uint4*)(p + q4 * 8);
                u32 ww[4] = {qq.x, qq.y, qq.z, qq.w};
#pragma unroll
                for (int q = 0; q < 4; ++q) {
                    g[q4 * 8 + q * 2] += __uint_as_float(ww[q] << 16);
                    g[q4 * 8 + q * 2 + 1] += __uint_as_float(ww[q] & 0xFFFF0000u);
                }
            }
        }
        float sc = (e1 > e0) ? 1.f / (float)(e1 - e0) : 0.f;
        if (gtc == 0) (half ? m2s : m1s)[grow] = (e1 > e0) ? 1.f : 0.f;
#pragma unroll
        for (int j = 0; j < 32; ++j) Asm[grow][gtc * 32 + j] = g[j] * sc;

        for (int kt = 0; kt < 4; ++kt) {
#pragma unroll
            for (int it = 0; it < 16; ++it) {
                int id = t + 256 * it;
                int kk = id >> 7, h = id & 127;
                Bsm[kk][h] = Wt[(half * 128 + kt * 32 + kk) * 128 + h];
            }
            __syncthreads();
#pragma unroll
            for (int kk = 0; kk < 32; ++kk) {
                float av[4];
#pragma unroll
                for (int i = 0; i < 4; ++i) av[i] = Asm[tm * 4 + i][kt * 32 + kk];
                const float4 b0 = *(const float4*)&Bsm[kk][tn * 8];
                const float4 b1 = *(const float4*)&Bsm[kk][tn * 8 + 4];
                float bv[8] = {b0.x, b0.y, b0.z, b0.w, b1.x, b1.y, b1.z, b1.w};
#pragma unroll
                for (int i = 0; i < 4; ++i)
#pragma unroll
                    for (int j = 0; j < 8; ++j)
                        acc[i][j] = fmaf(av[i], bv[j], acc[i][j]);
            }
            __syncthreads();
        }
    }

    // epilogue: bias + masks + relu + stats
    float bb[8], bm1[8], bm2[8];
#pragma unroll
    for (int j = 0; j < 8; ++j) {
        int h = tn * 8 + j;
        bb[j] = biasv[h];
        bm1[j] = biasv[128 + h];
        bm2[j] = biasv[256 + h];
    }
    float ps[8] = {0, 0, 0, 0, 0, 0, 0, 0};
    float pq[8] = {0, 0, 0, 0, 0, 0, 0, 0};
#pragma unroll
    for (int i = 0; i < 4; ++i) {
        int row = tm * 4 + i;
        float m1 = m1s[row], m2 = m2s[row];
        float vals[8];
#pragma unroll
        for (int j = 0; j < 8; ++j) {
            float v = acc[i][j] + bb[j] + m1 * bm1[j] + m2 * bm2[j];
            v = fmaxf(v, 0.f);
            ps[j] += v;
            pq[j] += v * v;
            vals[j] = v;
        }
        store8v(&Out[(size_t)(n0 + row) * 128 + tn * 8], vals);
    }
    // block reduction of stats (reuse LDS; safe after last syncthreads)
    float* redS = &Bsm[0][0];
    float* redQ = &Asm[0][0];
#pragma unroll
    for (int j = 0; j < 8; ++j) {
        redS[tm * 128 + tn * 8 + j] = ps[j];
        redQ[tm * 128 + tn * 8 + j] = pq[j];
    }
    __syncthreads();
    if (t < 128) {
        float s = 0.f, q = 0.f;
#pragma unroll
        for (int g2 = 0; g2 < 16; ++g2) {
            s += redS[g2 * 128 + t];
            q += redQ[g2 * 128 + t];
        }
        atomicAdd(&ssum[t], s);
        atomicAdd(&ssq[t], q);
    }
}

// ---------------------------------------------------------------------------
// launch
// ---------------------------------------------------------------------------
extern "C" void kernel_launch(void* const* d_in, const int* in_sizes, int n_in,
                              void* d_out, int out_size, void* d_ws, size_t ws_size,
                              hipStream_t stream) {
    const float* nodes = (const float*)d_in[0];
    const int* r2e = (const int*)d_in[1];
    const int* p2e = (const int*)d_in[2];
    const int* e2r = (const int*)d_in[3];
    const int* e2p = (const int*)d_in[4];
    const float* w_rct = (const float*)d_in[5];
    const float* b_rct = (const float*)d_in[6];
    const float* w_prd = (const float*)d_in[7];
    const float* b_prd = (const float*)d_in[8];
    const float* w_ra1 = (const float*)d_in[9];
    const float* b_ra1 = (const float*)d_in[10];
    const float* bn_r_g = (const float*)d_in[11];
    const float* bn_r_b = (const float*)d_in[12];
    const float* w_ra2 = (const float*)d_in[13];
    const float* b_ra2 = (const float*)d_in[14];
    const float* w_r2rct = (const float*)d_in[15];
    const float* b_r2rct = (const float*)d_in[16];
    const float* w_r2prd = (const float*)d_in[17];
    const float* b_r2prd = (const float*)d_in[18];
    const float* w_ma1 = (const float*)d_in[19];
    const float* b_ma1 = (const float*)d_in[20];
    const float* bn_m_g = (const float*)d_in[21];
    const float* bn_m_b = (const float*)d_in[22];
    const float* w_ma2 = (const float*)d_in[23];
    const float* b_ma2 = (const float*)d_in[24];

    char* ws = (char*)d_ws;
    size_t off = 0;
    auto alloc = [&](size_t bytes) -> char* {
        off = (off + 255) & ~(size_t)255;
        char* p = ws + off;
        off += bytes;
        return p;
    };

    // h1: B*R*128 bf16 = 102.4 MB (later reused as GEMM5 output tmp, 81.92 MB)
    const size_t H1B = (size_t)NB * NR * 128 * 2;
    __hip_bfloat16* h1 = (__hip_bfloat16*)alloc(H1B);
    float* outtmp = (float*)h1;  // alias: h1 dead when GEMM5 runs

    // CSR arrays
    char* cntcur = alloc((size_t)8 * (NR + NR + NM + NM));  // counts + cursors
    int* cnt_r = (int*)cntcur;
    int* cnt_p = cnt_r + NR;
    int* cnt_er = cnt_p + NR;
    int* cnt_ep = cnt_er + NM;
    int* cur_r = cnt_ep + NM;
    int* cur_p = cur_r + NR;
    int* cur_er = cur_p + NR;
    int* cur_ep = cur_er + NM;
    int* off_r = (int*)alloc((NR + 1) * 4);
    int* off_p = (int*)alloc((NR + 1) * 4);
    int* off_er = (int*)alloc((NM + 1) * 4);
    int* off_ep = (int*)alloc((NM + 1) * 4);
    int* idx_r = (int*)alloc(NE * 4);
    int* idx_p = (int*)alloc(NE * 4);
    int* idx_er = (int*)alloc(NE * 4);
    int* idx_ep = (int*)alloc(NE * 4);

    // stats + folded weights
    float* statblk = (float*)alloc(4 * 128 * 4);
    float* sum1 = statblk;
    float* sq1 = statblk + 128;
    float* sum2 = statblk + 256;
    float* sq2 = statblk + 384;
    float* Wt0_r = (float*)alloc(128 * 128 * 4);
    float* Wt0_p = (float*)alloc(128 * 128 * 4);
    float* Wt1 = (float*)alloc(256 * 128 * 4);
    float* bias1 = (float*)alloc(3 * 128 * 4);
    float* W2p = (float*)alloc(128 * 128 * 4);
    float* b2p = (float*)alloc(128 * 4);
    float* Wc_r = (float*)alloc(128 * 128 * 4);
    float* bc_r = (float*)alloc(128 * 4);
    float* Wc_p = (float*)alloc(128 * 128 * 4);
    float* bc_p = (float*)alloc(128 * 4);
    float* Wt2 = (float*)alloc(256 * 128 * 4);
    float* bias2 = (float*)alloc(3 * 128 * 4);
    float* WoutT = (float*)alloc(128 * 128 * 4);
    float* b_out = (float*)alloc(128 * 4);
    (void)ws_size;  // if insufficient we want a visible fault, not silent zeros

    // hid (B,M,256 bf16) lives in d_out; later d_out holds h2 (B,M,128 f32)
    __hip_bfloat16* hid = (__hip_bfloat16*)d_out;
    float* h2 = (float*)d_out;

    // ---- zero counters/stats ----
    hipMemsetAsync(cntcur, 0, (size_t)8 * (NR + NR + NM + NM), stream);
    hipMemsetAsync(statblk, 0, 4 * 128 * 4, stream);

    // ---- CSR build ----
    const int EB = (NE + 255) / 256;
    hist_k<<<EB, 256, 0, stream>>>(r2e + NE, cnt_r, NE);
    hist_k<<<EB, 256, 0, stream>>>(p2e + NE, cnt_p, NE);
    hist_k<<<EB, 256, 0, stream>>>(e2r + NE, cnt_er, NE);
    hist_k<<<EB, 256, 0, stream>>>(e2p + NE, cnt_ep, NE);
    scan4_k<<<4, 1024, 0, stream>>>(cnt_r, off_r, NR, cnt_p, off_p, NR,
                                    cnt_er, off_er, NM, cnt_ep, off_ep, NM);
    fill_k<<<EB, 256, 0, stream>>>(r2e, off_r, cur_r, idx_r, NE);
    fill_k<<<EB, 256, 0, stream>>>(p2e, off_p, cur_p, idx_p, NE);
    fill_k<<<EB, 256, 0, stream>>>(e2r, off_er, cur_er, idx_er, NE);
    fill_k<<<EB, 256, 0, stream>>>(e2p, off_ep, cur_ep, idx_ep, NE);

    // ---- GEMM1: hid[b,m,0:128]=nodes@w_rct^T ; [128:256]=nodes@w_prd^T (bf16) ----
    transpose_k<<<128, 128, 0, stream>>>(w_rct, Wt0_r);
    transpose_k<<<128, 128, 0, stream>>>(w_prd, Wt0_p);
    gemm_dense<__hip_bfloat16, false><<<(NB * NM) / 64, 256, 0, stream>>>(
        nodes, Wt0_r, nullptr, hid, 256, 0);
    gemm_dense<__hip_bfloat16, false><<<(NB * NM) / 64, 256, 0, stream>>>(
        nodes, Wt0_p, nullptr, hid, 256, 128);

    // ---- GEMM2: h1 = relu(gather(hid)@Wt1 + biases), bf16 + BN1 stats ----
    prep_w1_k<<<256, 128, 0, stream>>>(w_ra1, b_ra1, b_rct, b_prd, Wt1, bias1);
    gemm_gather<__hip_bfloat16><<<(NB * NR) / 64, 256, 0, stream>>>(
        hid, 256, 128, NM, NR, off_r, idx_r, off_p, idx_p, Wt1, bias1, h1, sum1, sq1);

    // ---- fold BN1 -> w_ra2 -> w_r2rct/w_r2prd -> w_ma1 ----
    prep2a_k<<<1, 128, 0, stream>>>(sum1, sq1, bn_r_g, bn_r_b, w_ra2, b_ra2,
                                    (float)((size_t)NB * NR), W2p, b2p);
    prep2b_k<<<256, 128, 0, stream>>>(w_r2rct, b_r2rct, w_r2prd, b_r2prd, W2p, b2p,
                                      Wc_r, bc_r, Wc_p, bc_p);
    prep1_k<<<256, 128, 0, stream>>>(Wc_r, Wc_p, w_ma1, bc_r, bc_p, b_ma1, Wt2, bias2);

    // ---- GEMM4: h2 = relu(gather(h1)@Wt2 + biases), f32 into d_out + BN2 stats ----
    gemm_gather<float><<<(NB * NM) / 64, 256, 0, stream>>>(
        h1, 128, 0, NR, NM, off_er, idx_er, off_ep, idx_ep, Wt2, bias2, h2, sum2, sq2);

    // ---- fold BN2 into w_ma2; GEMM5 into tmp; copy to d_out ----
    prep3_k<<<1, 128, 0, stream>>>(sum2, sq2, bn_m_g, bn_m_b, w_ma2, b_ma2,
                                   (float)((size_t)NB * NM), WoutT, b_out);
    gemm_dense<float, true><<<(NB * NM) / 64, 256, 0, stream>>>(
        h2, WoutT, b_out, outtmp, 128, 0);
    hipMemcpyAsync(d_out, outtmp, (size_t)NB * NM * 128 * 4,
                   hipMemcpyDeviceToDevice, stream);
}

// Round 3
// 711.094 us; speedup vs baseline: 1.5081x; 1.5081x over previous
//
#include <hip/hip_runtime.h>
#include <hip/hip_bf16.h>

#define NB 8
#define NM 20000
#define NR 50000
#define NE 100000
#define BN_EPS 1e-5f

typedef unsigned int u32;

using short8 = __attribute__((ext_vector_type(8))) short;  // 8 bf16
using f32x4 = __attribute__((ext_vector_type(4))) float;

#define MFMA16(a, b, c) __builtin_amdgcn_mfma_f32_16x16x32_bf16(a, b, c, 0, 0, 0)

struct alignas(16) BF16x8 { __hip_bfloat16 v[8]; };

__device__ inline void store8v(__hip_bfloat16* p, const float* v) {
    BF16x8 pk;
#pragma unroll
    for (int j = 0; j < 8; ++j) pk.v[j] = __float2bfloat16(v[j]);
    *(BF16x8*)p = pk;
}
__device__ inline void store8v(float* p, const float* v) {
    *(float4*)p = make_float4(v[0], v[1], v[2], v[3]);
    *(float4*)(p + 4) = make_float4(v[4], v[5], v[6], v[7]);
}

__device__ inline u32 f2bf_bits(float f) {
    u32 x = __float_as_uint(f);
    return (x + 0x7fffu + ((x >> 16) & 1u)) >> 16;
}
__device__ inline void storev(float* p, float v) { *p = v; }
__device__ inline void storev(__hip_bfloat16* p, float v) {
    *(unsigned short*)p = (unsigned short)f2bf_bits(v);
}

// ---------------------------------------------------------------------------
// CSR build: histogram, 4-list scan, fill
// ---------------------------------------------------------------------------
__global__ __launch_bounds__(256) void hist_k(const int* __restrict__ dst,
                                              int* __restrict__ cnt, int n) {
    int i = blockIdx.x * 256 + threadIdx.x;
    if (i < n) atomicAdd(&cnt[dst[i]], 1);
}

__global__ __launch_bounds__(1024) void scan4_k(
    const int* c0, int* o0, int n0, const int* c1, int* o1, int n1,
    const int* c2, int* o2, int n2, const int* c3, int* o3, int n3) {
    const int* c; int* o; int n;
    if (blockIdx.x == 0) { c = c0; o = o0; n = n0; }
    else if (blockIdx.x == 1) { c = c1; o = o1; n = n1; }
    else if (blockIdx.x == 2) { c = c2; o = o2; n = n2; }
    else { c = c3; o = o3; n = n3; }
    __shared__ int wsum[16];
    __shared__ int carry_s;
    int t = threadIdx.x, lane = t & 63, w = t >> 6;
    if (t == 0) carry_s = 0;
    __syncthreads();
    for (int base = 0; base < n; base += 1024) {
        int i = base + t;
        int x = (i < n) ? c[i] : 0;
#pragma unroll
        for (int s = 1; s < 64; s <<= 1) {
            int y = __shfl_up(x, s);
            if (lane >= s) x += y;
        }
        if (lane == 63) wsum[w] = x;
        __syncthreads();
        if (w == 0) {
            int ws = (lane < 16) ? wsum[lane] : 0;
#pragma unroll
            for (int s = 1; s < 16; s <<= 1) {
                int y = __shfl_up(ws, s);
                if (lane >= s) ws += y;
            }
            if (lane < 16) wsum[lane] = ws;
        }
        __syncthreads();
        int wbase = (w > 0) ? wsum[w - 1] : 0;
        int incl = x + wbase + carry_s;
        if (i < n) o[i + 1] = incl;
        __syncthreads();
        if (t == 1023) carry_s = incl;
        __syncthreads();
    }
    if (t == 0) o[0] = 0;
}

__global__ __launch_bounds__(256) void fill_k(const int* __restrict__ edges,
                                              const int* __restrict__ off,
                                              int* __restrict__ cur,
                                              int* __restrict__ idx, int n) {
    int i = blockIdx.x * 256 + threadIdx.x;
    if (i < n) {
        int d = edges[n + i];
        int p = atomicAdd(&cur[d], 1);
        idx[off[d] + p] = edges[i];
    }
}

// ---------------------------------------------------------------------------
// weight preps
// ---------------------------------------------------------------------------
__global__ __launch_bounds__(128) void transpose_k(const float* __restrict__ w,
                                                   float* __restrict__ wt) {
    int k = blockIdx.x, h = threadIdx.x;
    wt[k * 128 + h] = w[h * 128 + k];
}

__global__ __launch_bounds__(128) void prep_w1_k(const float* __restrict__ w_ra1,
                                                 const float* __restrict__ b_ra1,
                                                 const float* __restrict__ b_rct,
                                                 const float* __restrict__ b_prd,
                                                 float* __restrict__ Wt1,
                                                 float* __restrict__ bias1) {
    int k = blockIdx.x, h = threadIdx.x;
    Wt1[k * 128 + h] = w_ra1[h * 128 + (k & 127)];
    if (k == 0) {
        float s1 = 0.f, s2 = 0.f;
        for (int j = 0; j < 128; ++j) {
            float w = w_ra1[h * 128 + j];
            s1 = fmaf(w, b_rct[j], s1);
            s2 = fmaf(w, b_prd[j], s2);
        }
        bias1[h] = b_ra1[h];
        bias1[128 + h] = s1;
        bias1[256 + h] = s2;
    }
}

__global__ __launch_bounds__(128) void prep2a_k(const float* __restrict__ ssum,
                                                const float* __restrict__ ssq,
                                                const float* __restrict__ g,
                                                const float* __restrict__ beta,
                                                const float* __restrict__ w_ra2,
                                                const float* __restrict__ b_ra2,
                                                float Nf, float* __restrict__ W2p,
                                                float* __restrict__ b2p) {
    int h = threadIdx.x;
    __shared__ float t1[128];
    float mean = ssum[h] / Nf;
    float var = ssq[h] / Nf - mean * mean;
    float sv = g[h] * rsqrtf(var + BN_EPS);
    t1[h] = beta[h] - mean * sv;
    for (int r = 0; r < 128; ++r) W2p[r * 128 + h] = w_ra2[r * 128 + h] * sv;
    __syncthreads();
    float sb = 0.f;
    for (int d = 0; d < 128; ++d) sb = fmaf(t1[d], w_ra2[h * 128 + d], sb);
    b2p[h] = sb + b_ra2[h];
}

__global__ __launch_bounds__(128) void prep2b_k(const float* __restrict__ w_r2rct,
                                                const float* __restrict__ b_r2rct,
                                                const float* __restrict__ w_r2prd,
                                                const float* __restrict__ b_r2prd,
                                                const float* __restrict__ W2p,
                                                const float* __restrict__ b2p,
                                                float* __restrict__ Wc_r,
                                                float* __restrict__ bc_r,
                                                float* __restrict__ Wc_p,
                                                float* __restrict__ bc_p) {
    int blk = blockIdx.x;
    int d = threadIdx.x;
    int h = blk & 127;
    bool second = blk >= 128;
    const float* w = second ? w_r2prd : w_r2rct;
    const float* bsrc = second ? b_r2prd : b_r2rct;
    float* Wc = second ? Wc_p : Wc_r;
    float* bc = second ? bc_p : bc_r;
    __shared__ float rowv[128];
    __shared__ float red[128];
    rowv[d] = w[h * 128 + d];
    __syncthreads();
    float s = 0.f;
#pragma unroll 4
    for (int j = 0; j < 128; ++j) s = fmaf(rowv[j], W2p[j * 128 + d], s);
    Wc[h * 128 + d] = s;
    red[d] = rowv[d] * b2p[d];
    __syncthreads();
    for (int off = 64; off > 0; off >>= 1) {
        if (d < off) red[d] += red[d + off];
        __syncthreads();
    }
    if (d == 0) bc[h] = red[0] + bsrc[h];
}

__global__ __launch_bounds__(128) void prep1_k(const float* __restrict__ w_s1,
                                               const float* __restrict__ w_s2,
                                               const float* __restrict__ w_big,
                                               const float* __restrict__ b_s1,
                                               const float* __restrict__ b_s2,
                                               const float* __restrict__ b_big,
                                               float* __restrict__ Wt,
                                               float* __restrict__ bias) {
    int k = blockIdx.x;
    int h = threadIdx.x;
    __shared__ float col[128];
    const float* wsrc = (k < 128) ? w_s1 : w_s2;
    int kk = k & 127;
    col[h] = wsrc[h * 128 + kk];
    __syncthreads();
    float s = 0.f;
#pragma unroll 4
    for (int j = 0; j < 128; ++j) s = fmaf(w_big[h * 128 + j], col[j], s);
    Wt[k * 128 + h] = s;
    if (k == 0) {
        float sb1 = 0.f, sb2 = 0.f;
        for (int j = 0; j < 128; ++j) {
            sb1 = fmaf(w_big[h * 128 + j], b_s1[j], sb1);
            sb2 = fmaf(w_big[h * 128 + j], b_s2[j], sb2);
        }
        bias[h] = b_big[h];
        bias[128 + h] = sb1;
        bias[256 + h] = sb2;
    }
}

__global__ __launch_bounds__(128) void prep3_k(const float* __restrict__ ssum,
                                               const float* __restrict__ ssq,
                                               const float* __restrict__ g,
                                               const float* __restrict__ beta,
                                               const float* __restrict__ w_ma2,
                                               const float* __restrict__ b_ma2,
                                               float Nf, float* __restrict__ WoutT,
                                               float* __restrict__ b_out) {
    int h = threadIdx.x;
    __shared__ float s2[128], t2[128];
    float mean = ssum[h] / Nf;
    float var = ssq[h] / Nf - mean * mean;
    float sv = g[h] * rsqrtf(var + BN_EPS);
    s2[h] = sv;
    t2[h] = beta[h] - mean * sv;
    __syncthreads();
    for (int k = 0; k < 128; ++k) WoutT[k * 128 + h] = w_ma2[h * 128 + k] * s2[k];
    float sb = 0.f;
    for (int k = 0; k < 128; ++k) sb = fmaf(t2[k], w_ma2[h * 128 + k], sb);
    b_out[h] = sb + b_ma2[h];
}

// Repack Wt (K x 128, k-major fp32, K=256) into bf16 B-fragment order:
// WtB[((ntile*8 + kstep)*64 + lane)*8 + j] = bf16(Wt[kstep*32 + (lane>>4)*8 + j][ntile*16 + (lane&15)])
__global__ __launch_bounds__(256) void repack_b_k(const float* __restrict__ Wt,
                                                  short* __restrict__ WtB) {
    int id = blockIdx.x * 256 + threadIdx.x;  // 0..32767
    int k = id >> 7, h = id & 127;
    float v = Wt[k * 128 + h];
    int ks = k >> 5, hi = (k >> 3) & 3, j = k & 7;
    int ntile = h >> 4, lc = h & 15;
    int lane = hi * 16 + lc;
    WtB[((ntile * 8 + ks) * 64 + lane) * 8 + j] = (short)f2bf_bits(v);
}

// ---------------------------------------------------------------------------
// dense GEMM (VALU fp32): Out[n, coloff+0:128] = A[n,0:128]@Wt (+bias)
// ---------------------------------------------------------------------------
template <typename OT, bool BIAS>
__global__ __launch_bounds__(256) void gemm_dense(const float* __restrict__ A,
                                                  const float* __restrict__ Wt,
                                                  const float* __restrict__ bias,
                                                  OT* __restrict__ Out, int ldo,
                                                  int coloff) {
    __shared__ float Asm[64][36];
    __shared__ float Bsm[32][132];
    const int t = threadIdx.x;
    const int n0 = blockIdx.x * 64;
    const int tn = t & 15, tm = t >> 4;
    float acc[4][8];
#pragma unroll
    for (int i = 0; i < 4; ++i)
#pragma unroll
        for (int j = 0; j < 8; ++j) acc[i][j] = 0.f;

    for (int kt = 0; kt < 4; ++kt) {
#pragma unroll
        for (int it = 0; it < 16; ++it) {
            int id = t + 256 * it;
            int kk = id >> 7, h = id & 127;
            Bsm[kk][h] = Wt[(kt * 32 + kk) * 128 + h];
        }
#pragma unroll
        for (int it = 0; it < 8; ++it) {
            int id = t + 256 * it;
            int row = id >> 5, kk = id & 31;
            Asm[row][kk] = A[(size_t)(n0 + row) * 128 + kt * 32 + kk];
        }
        __syncthreads();
#pragma unroll
        for (int kk = 0; kk < 32; ++kk) {
            float av[4];
#pragma unroll
            for (int i = 0; i < 4; ++i) av[i] = Asm[tm * 4 + i][kk];
            const float4 b0 = *(const float4*)&Bsm[kk][tn * 8];
            const float4 b1 = *(const float4*)&Bsm[kk][tn * 8 + 4];
            float bv[8] = {b0.x, b0.y, b0.z, b0.w, b1.x, b1.y, b1.z, b1.w};
#pragma unroll
            for (int i = 0; i < 4; ++i)
#pragma unroll
                for (int j = 0; j < 8; ++j) acc[i][j] = fmaf(av[i], bv[j], acc[i][j]);
        }
        __syncthreads();
    }
    float bb[8];
#pragma unroll
    for (int j = 0; j < 8; ++j) bb[j] = BIAS ? bias[tn * 8 + j] : 0.f;
#pragma unroll
    for (int i = 0; i < 4; ++i) {
        float vals[8];
#pragma unroll
        for (int j = 0; j < 8; ++j) vals[j] = acc[i][j] + bb[j];
        store8v(&Out[(size_t)(n0 + tm * 4 + i) * ldo + coloff + tn * 8], vals);
    }
}

// ---------------------------------------------------------------------------
// MFMA gather GEMM: per row n (b=n/nbins, r=n%nbins):
//   A[:,0:128]   = mean over CSR1[r] of src[b, idx, half0 cols]
//   A[:,128:256] = mean over CSR2[r] of src[b, idx, half1 cols]
//   Out = relu(A @ W(256x128) + base + m1*bm1 + m2*bm2), + BN stats
// 256 threads = 4 waves; 64x128 tile; wave w: rows all, cols [w*32, w*32+32)
// A staged bf16 in LDS [64][264] (132-word row stride: conflict-free b128)
// B pre-packed fragments, held in VGPRs (16 x short8 per wave)
// ---------------------------------------------------------------------------
template <typename OT>
__global__ __launch_bounds__(256) void gemm_gather_mfma(
    const __hip_bfloat16* __restrict__ src, int srcw, int h2off, int nsrc, int nbins,
    const int* __restrict__ off1, const int* __restrict__ idx1,
    const int* __restrict__ off2, const int* __restrict__ idx2,
    const short* __restrict__ WtB, const float* __restrict__ biasv,
    OT* __restrict__ Out, float* __restrict__ ssum, float* __restrict__ ssq) {
    __shared__ alignas(16) short Asm[64][264];
    __shared__ float m1s[64], m2s[64];

    const int t = threadIdx.x, n0 = blockIdx.x * 64;
    const int lane = t & 63;
    const int w = t >> 6;
    const int lrow = lane & 15;  // A-row-in-tile / C col
    const int lhi = lane >> 4;   // 0..3

    // ---- B fragments: wave w covers col-tiles {2w, 2w+1} ----
    short8 bfrag[2][8];
#pragma unroll
    for (int c2 = 0; c2 < 2; ++c2) {
        const short* bp = WtB + (size_t)(((w * 2 + c2) * 8) * 64 + lane) * 8;
#pragma unroll
        for (int ks = 0; ks < 8; ++ks) bfrag[c2][ks] = *(const short8*)(bp + ks * 512);
    }

    // ---- gather phase: 4 threads per row, each covers 32 cols per half ----
    {
        const int grow = t >> 2, gtc = t & 3;
        const int n = n0 + grow;
        const int b = n / nbins;
        const int r = n - b * nbins;
#pragma unroll
        for (int half = 0; half < 2; ++half) {
            const int* off = half ? off2 : off1;
            const int* idx = half ? idx2 : idx1;
            int e0 = off[r], e1 = off[r + 1];
            float g[32];
#pragma unroll
            for (int j = 0; j < 32; ++j) g[j] = 0.f;
            const __hip_bfloat16* base =
                src + (size_t)b * nsrc * srcw + (half ? h2off : 0) + gtc * 32;
            for (int e = e0; e < e1; ++e) {
                const __hip_bfloat16* p = base + (size_t)idx[e] * srcw;
#pragma unroll
                for (int q4 = 0; q4 < 4; ++q4) {
                    uint4 qq = *(const uint4*)(p + q4 * 8);
                    u32 ww[4] = {qq.x, qq.y, qq.z, qq.w};
#pragma unroll
                    for (int q = 0; q < 4; ++q) {
                        g[q4 * 8 + q * 2] += __uint_as_float(ww[q] << 16);
                        g[q4 * 8 + q * 2 + 1] += __uint_as_float(ww[q] & 0xFFFF0000u);
                    }
                }
            }
            float sc = (e1 > e0) ? 1.f / (float)(e1 - e0) : 0.f;
            if (gtc == 0) (half ? m2s : m1s)[grow] = (e1 > e0) ? 1.f : 0.f;
            // pack to bf16 pairs and store 4 x b128 to LDS
            u32* aw = (u32*)&Asm[0][0];
            int wbase = grow * 132 + half * 64 + gtc * 16;
#pragma unroll
            for (int c = 0; c < 4; ++c) {
                u32 pk[4];
#pragma unroll
                for (int q = 0; q < 4; ++q) {
                    float v0 = g[c * 8 + q * 2] * sc;
                    float v1 = g[c * 8 + q * 2 + 1] * sc;
                    pk[q] = f2bf_bits(v0) | (f2bf_bits(v1) << 16);
                }
                *(uint4*)&aw[wbase + c * 4] = make_uint4(pk[0], pk[1], pk[2], pk[3]);
            }
        }
    }
    __syncthreads();

    // ---- MFMA: 4 row-tiles x 2 col-tiles x 8 k-steps ----
    f32x4 acc[4][2];
#pragma unroll
    for (int rt = 0; rt < 4; ++rt)
#pragma unroll
        for (int c2 = 0; c2 < 2; ++c2) acc[rt][c2] = (f32x4){0.f, 0.f, 0.f, 0.f};

#pragma unroll
    for (int rt = 0; rt < 4; ++rt) {
#pragma unroll
        for (int ks = 0; ks < 8; ++ks) {
            short8 af = *(const short8*)&Asm[rt * 16 + lrow][ks * 32 + lhi * 8];
            acc[rt][0] = MFMA16(af, bfrag[0][ks], acc[rt][0]);
            acc[rt][1] = MFMA16(af, bfrag[1][ks], acc[rt][1]);
        }
    }

    // ---- epilogue: bias + masks + relu + stats + store ----
#pragma unroll
    for (int c2 = 0; c2 < 2; ++c2) {
        int col = (w * 2 + c2) * 16 + lrow;
        float bb = biasv[col], bm1 = biasv[128 + col], bm2 = biasv[256 + col];
        float ps = 0.f, pq = 0.f;
#pragma unroll
        for (int rt = 0; rt < 4; ++rt) {
#pragma unroll
            for (int i = 0; i < 4; ++i) {
                int row = rt * 16 + lhi * 4 + i;
                float v = acc[rt][c2][i] + bb + m1s[row] * bm1 + m2s[row] * bm2;
                v = fmaxf(v, 0.f);
                ps += v;
                pq += v * v;
                storev(&Out[(size_t)(n0 + row) * 128 + col], v);
            }
        }
        ps += __shfl_xor(ps, 16);
        ps += __shfl_xor(ps, 32);
        pq += __shfl_xor(pq, 16);
        pq += __shfl_xor(pq, 32);
        if (lhi == 0) {
            atomicAdd(&ssum[col], ps);
            atomicAdd(&ssq[col], pq);
        }
    }
}

// ---------------------------------------------------------------------------
// launch
// ---------------------------------------------------------------------------
extern "C" void kernel_launch(void* const* d_in, const int* in_sizes, int n_in,
                              void* d_out, int out_size, void* d_ws, size_t ws_size,
                              hipStream_t stream) {
    const float* nodes = (const float*)d_in[0];
    const int* r2e = (const int*)d_in[1];
    const int* p2e = (const int*)d_in[2];
    const int* e2r = (const int*)d_in[3];
    const int* e2p = (const int*)d_in[4];
    const float* w_rct = (const float*)d_in[5];
    const float* b_rct = (const float*)d_in[6];
    const float* w_prd = (const float*)d_in[7];
    const float* b_prd = (const float*)d_in[8];
    const float* w_ra1 = (const float*)d_in[9];
    const float* b_ra1 = (const float*)d_in[10];
    const float* bn_r_g = (const float*)d_in[11];
    const float* bn_r_b = (const float*)d_in[12];
    const float* w_ra2 = (const float*)d_in[13];
    const float* b_ra2 = (const float*)d_in[14];
    const float* w_r2rct = (const float*)d_in[15];
    const float* b_r2rct = (const float*)d_in[16];
    const float* w_r2prd = (const float*)d_in[17];
    const float* b_r2prd = (const float*)d_in[18];
    const float* w_ma1 = (const float*)d_in[19];
    const float* b_ma1 = (const float*)d_in[20];
    const float* bn_m_g = (const float*)d_in[21];
    const float* bn_m_b = (const float*)d_in[22];
    const float* w_ma2 = (const float*)d_in[23];
    const float* b_ma2 = (const float*)d_in[24];

    char* ws = (char*)d_ws;
    size_t off = 0;
    auto alloc = [&](size_t bytes) -> char* {
        off = (off + 255) & ~(size_t)255;
        char* p = ws + off;
        off += bytes;
        return p;
    };

    const size_t H1B = (size_t)NB * NR * 128 * 2;  // 102.4 MB
    __hip_bfloat16* h1 = (__hip_bfloat16*)alloc(H1B);

    char* cntcur = alloc((size_t)8 * (NR + NR + NM + NM));
    int* cnt_r = (int*)cntcur;
    int* cnt_p = cnt_r + NR;
    int* cnt_er = cnt_p + NR;
    int* cnt_ep = cnt_er + NM;
    int* cur_r = cnt_ep + NM;
    int* cur_p = cur_r + NR;
    int* cur_er = cur_p + NR;
    int* cur_ep = cur_er + NM;
    int* off_r = (int*)alloc((NR + 1) * 4);
    int* off_p = (int*)alloc((NR + 1) * 4);
    int* off_er = (int*)alloc((NM + 1) * 4);
    int* off_ep = (int*)alloc((NM + 1) * 4);
    int* idx_r = (int*)alloc(NE * 4);
    int* idx_p = (int*)alloc(NE * 4);
    int* idx_er = (int*)alloc(NE * 4);
    int* idx_ep = (int*)alloc(NE * 4);

    float* statblk = (float*)alloc(4 * 128 * 4);
    float* sum1 = statblk;
    float* sq1 = statblk + 128;
    float* sum2 = statblk + 256;
    float* sq2 = statblk + 384;
    float* Wt0_r = (float*)alloc(128 * 128 * 4);
    float* Wt0_p = (float*)alloc(128 * 128 * 4);
    float* Wt1 = (float*)alloc(256 * 128 * 4);
    float* bias1 = (float*)alloc(3 * 128 * 4);
    float* W2p = (float*)alloc(128 * 128 * 4);
    float* b2p = (float*)alloc(128 * 4);
    float* Wc_r = (float*)alloc(128 * 128 * 4);
    float* bc_r = (float*)alloc(128 * 4);
    float* Wc_p = (float*)alloc(128 * 128 * 4);
    float* bc_p = (float*)alloc(128 * 4);
    float* Wt2 = (float*)alloc(256 * 128 * 4);
    float* bias2 = (float*)alloc(3 * 128 * 4);
    float* WoutT = (float*)alloc(128 * 128 * 4);
    float* b_out = (float*)alloc(128 * 4);
    short* WtB1 = (short*)alloc(256 * 128 * 2);
    short* WtB2 = (short*)alloc(256 * 128 * 2);
    (void)ws_size;

    // hid (B,M,256 bf16) and h2 (B,M,128 f32) both live in d_out (81.92 MB)
    __hip_bfloat16* hid = (__hip_bfloat16*)d_out;
    float* h2 = (float*)d_out;

    hipMemsetAsync(cntcur, 0, (size_t)8 * (NR + NR + NM + NM), stream);
    hipMemsetAsync(statblk, 0, 4 * 128 * 4, stream);

    // ---- CSR build ----
    const int EB = (NE + 255) / 256;
    hist_k<<<EB, 256, 0, stream>>>(r2e + NE, cnt_r, NE);
    hist_k<<<EB, 256, 0, stream>>>(p2e + NE, cnt_p, NE);
    hist_k<<<EB, 256, 0, stream>>>(e2r + NE, cnt_er, NE);
    hist_k<<<EB, 256, 0, stream>>>(e2p + NE, cnt_ep, NE);
    scan4_k<<<4, 1024, 0, stream>>>(cnt_r, off_r, NR, cnt_p, off_p, NR,
                                    cnt_er, off_er, NM, cnt_ep, off_ep, NM);
    fill_k<<<EB, 256, 0, stream>>>(r2e, off_r, cur_r, idx_r, NE);
    fill_k<<<EB, 256, 0, stream>>>(p2e, off_p, cur_p, idx_p, NE);
    fill_k<<<EB, 256, 0, stream>>>(e2r, off_er, cur_er, idx_er, NE);
    fill_k<<<EB, 256, 0, stream>>>(e2p, off_ep, cur_ep, idx_ep, NE);

    // ---- GEMM1: hid = [nodes@w_rct^T | nodes@w_prd^T] (bf16) ----
    transpose_k<<<128, 128, 0, stream>>>(w_rct, Wt0_r);
    transpose_k<<<128, 128, 0, stream>>>(w_prd, Wt0_p);
    gemm_dense<__hip_bfloat16, false><<<(NB * NM) / 64, 256, 0, stream>>>(
        nodes, Wt0_r, nullptr, hid, 256, 0);
    gemm_dense<__hip_bfloat16, false><<<(NB * NM) / 64, 256, 0, stream>>>(
        nodes, Wt0_p, nullptr, hid, 256, 128);

    // ---- GEMM2 (MFMA): h1 = relu(gather(hid)@Wt1 + biases) + BN1 stats ----
    prep_w1_k<<<256, 128, 0, stream>>>(w_ra1, b_ra1, b_rct, b_prd, Wt1, bias1);
    repack_b_k<<<128, 256, 0, stream>>>(Wt1, WtB1);
    gemm_gather_mfma<__hip_bfloat16><<<(NB * NR) / 64, 256, 0, stream>>>(
        hid, 256, 128, NM, NR, off_r, idx_r, off_p, idx_p, WtB1, bias1, h1, sum1, sq1);

    // ---- fold BN1 -> w_ra2 -> w_r2rct/w_r2prd -> w_ma1 ----
    prep2a_k<<<1, 128, 0, stream>>>(sum1, sq1, bn_r_g, bn_r_b, w_ra2, b_ra2,
                                    (float)((size_t)NB * NR), W2p, b2p);
    prep2b_k<<<256, 128, 0, stream>>>(w_r2rct, b_r2rct, w_r2prd, b_r2prd, W2p, b2p,
                                      Wc_r, bc_r, Wc_p, bc_p);
    prep1_k<<<256, 128, 0, stream>>>(Wc_r, Wc_p, w_ma1, bc_r, bc_p, b_ma1, Wt2, bias2);
    repack_b_k<<<128, 256, 0, stream>>>(Wt2, WtB2);

    // ---- GEMM4 (MFMA): h2 = relu(gather(h1)@Wt2 + biases), f32 -> d_out ----
    gemm_gather_mfma<float><<<(NB * NM) / 64, 256, 0, stream>>>(
        h1, 128, 0, NR, NM, off_er, idx_er, off_ep, idx_ep, WtB2, bias2, h2, sum2, sq2);

    // ---- fold BN2; GEMM5 in-place on d_out (row-local, safe) ----
    prep3_k<<<1, 128, 0, stream>>>(sum2, sq2, bn_m_g, bn_m_b, w_ma2, b_ma2,
                                   (float)((size_t)NB * NM), WoutT, b_out);
    gemm_dense<float, true><<<(NB * NM) / 64, 256, 0, stream>>>(
        h2, WoutT, b_out, (float*)d_out, 128, 0);
}

// Round 4
// 503.166 us; speedup vs baseline: 2.1314x; 1.4132x over previous
//
#include <hip/hip_runtime.h>
#include <hip/hip_bf16.h>

#define NB 8
#define NM 20000
#define NR 50000
#define NE 100000
#define BN_EPS 1e-5f

typedef unsigned int u32;

using short8 = __attribute__((ext_vector_type(8))) short;  // 8 bf16
using f32x4 = __attribute__((ext_vector_type(4))) float;

#define MFMA16(a, b, c) __builtin_amdgcn_mfma_f32_16x16x32_bf16(a, b, c, 0, 0, 0)

__device__ inline u32 f2bf_bits(float f) {
    u32 x = __float_as_uint(f);
    return (x + 0x7fffu + ((x >> 16) & 1u)) >> 16;
}
__device__ inline void storev(float* p, float v) { *p = v; }
__device__ inline void storev(__hip_bfloat16* p, float v) {
    *(unsigned short*)p = (unsigned short)f2bf_bits(v);
}

// accumulate 32 bf16 cols into fp32
__device__ inline void acc32(const __hip_bfloat16* p, float* g) {
#pragma unroll
    for (int q4 = 0; q4 < 4; ++q4) {
        uint4 qq = *(const uint4*)(p + q4 * 8);
        u32 ww[4] = {qq.x, qq.y, qq.z, qq.w};
#pragma unroll
        for (int q = 0; q < 4; ++q) {
            g[q4 * 8 + q * 2] += __uint_as_float(ww[q] << 16);
            g[q4 * 8 + q * 2 + 1] += __uint_as_float(ww[q] & 0xFFFF0000u);
        }
    }
}

// ---------------------------------------------------------------------------
// CSR build
// ---------------------------------------------------------------------------
__global__ __launch_bounds__(256) void hist_k(const int* __restrict__ dst,
                                              int* __restrict__ cnt, int n) {
    int i = blockIdx.x * 256 + threadIdx.x;
    if (i < n) atomicAdd(&cnt[dst[i]], 1);
}

__global__ __launch_bounds__(1024) void scan4_k(
    const int* c0, int* o0, int n0, const int* c1, int* o1, int n1,
    const int* c2, int* o2, int n2, const int* c3, int* o3, int n3) {
    const int* c; int* o; int n;
    if (blockIdx.x == 0) { c = c0; o = o0; n = n0; }
    else if (blockIdx.x == 1) { c = c1; o = o1; n = n1; }
    else if (blockIdx.x == 2) { c = c2; o = o2; n = n2; }
    else { c = c3; o = o3; n = n3; }
    __shared__ int wsum[16];
    __shared__ int carry_s;
    int t = threadIdx.x, lane = t & 63, w = t >> 6;
    if (t == 0) carry_s = 0;
    __syncthreads();
    for (int base = 0; base < n; base += 1024) {
        int i = base + t;
        int x = (i < n) ? c[i] : 0;
#pragma unroll
        for (int s = 1; s < 64; s <<= 1) {
            int y = __shfl_up(x, s);
            if (lane >= s) x += y;
        }
        if (lane == 63) wsum[w] = x;
        __syncthreads();
        if (w == 0) {
            int ws = (lane < 16) ? wsum[lane] : 0;
#pragma unroll
            for (int s = 1; s < 16; s <<= 1) {
                int y = __shfl_up(ws, s);
                if (lane >= s) ws += y;
            }
            if (lane < 16) wsum[lane] = ws;
        }
        __syncthreads();
        int wbase = (w > 0) ? wsum[w - 1] : 0;
        int incl = x + wbase + carry_s;
        if (i < n) o[i + 1] = incl;
        __syncthreads();
        if (t == 1023) carry_s = incl;
        __syncthreads();
    }
    if (t == 0) o[0] = 0;
}

__global__ __launch_bounds__(256) void fill_k(const int* __restrict__ edges,
                                              const int* __restrict__ off,
                                              int* __restrict__ cur,
                                              int* __restrict__ idx, int n) {
    int i = blockIdx.x * 256 + threadIdx.x;
    if (i < n) {
        int d = edges[n + i];
        int p = atomicAdd(&cur[d], 1);
        idx[off[d] + p] = edges[i];
    }
}

// ---------------------------------------------------------------------------
// weight preps
// ---------------------------------------------------------------------------
// Wt1[k][h] = w_ra1[h][k&127]; bias1 = [b_ra1 | w_ra1@b_rct | w_ra1@b_prd]
__global__ __launch_bounds__(128) void prep_w1_k(const float* __restrict__ w_ra1,
                                                 const float* __restrict__ b_ra1,
                                                 const float* __restrict__ b_rct,
                                                 const float* __restrict__ b_prd,
                                                 float* __restrict__ Wt1,
                                                 float* __restrict__ bias1) {
    int k = blockIdx.x, h = threadIdx.x;
    Wt1[k * 128 + h] = w_ra1[h * 128 + (k & 127)];
    if (k == 0) {
        float s1 = 0.f, s2 = 0.f;
        for (int j = 0; j < 128; ++j) {
            float w = w_ra1[h * 128 + j];
            s1 = fmaf(w, b_rct[j], s1);
            s2 = fmaf(w, b_prd[j], s2);
        }
        bias1[h] = b_ra1[h];
        bias1[128 + h] = s1;
        bias1[256 + h] = s2;
    }
}

__global__ __launch_bounds__(128) void prep2a_k(const float* __restrict__ ssum,
                                                const float* __restrict__ ssq,
                                                const float* __restrict__ g,
                                                const float* __restrict__ beta,
                                                const float* __restrict__ w_ra2,
                                                const float* __restrict__ b_ra2,
                                                float Nf, float* __restrict__ W2p,
                                                float* __restrict__ b2p) {
    int h = threadIdx.x;
    __shared__ float t1[128];
    float mean = ssum[h] / Nf;
    float var = ssq[h] / Nf - mean * mean;
    float sv = g[h] * rsqrtf(var + BN_EPS);
    t1[h] = beta[h] - mean * sv;
    for (int r = 0; r < 128; ++r) W2p[r * 128 + h] = w_ra2[r * 128 + h] * sv;
    __syncthreads();
    float sb = 0.f;
    for (int d = 0; d < 128; ++d) sb = fmaf(t1[d], w_ra2[h * 128 + d], sb);
    b2p[h] = sb + b_ra2[h];
}

__global__ __launch_bounds__(128) void prep2b_k(const float* __restrict__ w_r2rct,
                                                const float* __restrict__ b_r2rct,
                                                const float* __restrict__ w_r2prd,
                                                const float* __restrict__ b_r2prd,
                                                const float* __restrict__ W2p,
                                                const float* __restrict__ b2p,
                                                float* __restrict__ Wc_r,
                                                float* __restrict__ bc_r,
                                                float* __restrict__ Wc_p,
                                                float* __restrict__ bc_p) {
    int blk = blockIdx.x;
    int d = threadIdx.x;
    int h = blk & 127;
    bool second = blk >= 128;
    const float* w = second ? w_r2prd : w_r2rct;
    const float* bsrc = second ? b_r2prd : b_r2rct;
    float* Wc = second ? Wc_p : Wc_r;
    float* bc = second ? bc_p : bc_r;
    __shared__ float rowv[128];
    __shared__ float red[128];
    rowv[d] = w[h * 128 + d];
    __syncthreads();
    float s = 0.f;
#pragma unroll 4
    for (int j = 0; j < 128; ++j) s = fmaf(rowv[j], W2p[j * 128 + d], s);
    Wc[h * 128 + d] = s;
    red[d] = rowv[d] * b2p[d];
    __syncthreads();
    for (int off = 64; off > 0; off >>= 1) {
        if (d < off) red[d] += red[d + off];
        __syncthreads();
    }
    if (d == 0) bc[h] = red[0] + bsrc[h];
}

__global__ __launch_bounds__(128) void prep1_k(const float* __restrict__ w_s1,
                                               const float* __restrict__ w_s2,
                                               const float* __restrict__ w_big,
                                               const float* __restrict__ b_s1,
                                               const float* __restrict__ b_s2,
                                               const float* __restrict__ b_big,
                                               float* __restrict__ Wt,
                                               float* __restrict__ bias) {
    int k = blockIdx.x;
    int h = threadIdx.x;
    __shared__ float col[128];
    const float* wsrc = (k < 128) ? w_s1 : w_s2;
    int kk = k & 127;
    col[h] = wsrc[h * 128 + kk];
    __syncthreads();
    float s = 0.f;
#pragma unroll 4
    for (int j = 0; j < 128; ++j) s = fmaf(w_big[h * 128 + j], col[j], s);
    Wt[k * 128 + h] = s;
    if (k == 0) {
        float sb1 = 0.f, sb2 = 0.f;
        for (int j = 0; j < 128; ++j) {
            sb1 = fmaf(w_big[h * 128 + j], b_s1[j], sb1);
            sb2 = fmaf(w_big[h * 128 + j], b_s2[j], sb2);
        }
        bias[h] = b_big[h];
        bias[128 + h] = sb1;
        bias[256 + h] = sb2;
    }
}

__global__ __launch_bounds__(128) void prep3_k(const float* __restrict__ ssum,
                                               const float* __restrict__ ssq,
                                               const float* __restrict__ g,
                                               const float* __restrict__ beta,
                                               const float* __restrict__ w_ma2,
                                               const float* __restrict__ b_ma2,
                                               float Nf, float* __restrict__ WoutT,
                                               float* __restrict__ b_out) {
    int h = threadIdx.x;
    __shared__ float s2[128], t2[128];
    float mean = ssum[h] / Nf;
    float var = ssq[h] / Nf - mean * mean;
    float sv = g[h] * rsqrtf(var + BN_EPS);
    s2[h] = sv;
    t2[h] = beta[h] - mean * sv;
    __syncthreads();
    for (int k = 0; k < 128; ++k) WoutT[k * 128 + h] = w_ma2[h * 128 + k] * s2[k];
    float sb = 0.f;
    for (int k = 0; k < 128; ++k) sb = fmaf(t2[k], w_ma2[h * 128 + k], sb);
    b_out[h] = sb + b_ma2[h];
}

// Repack k-major Wt (K x 128 fp32) to bf16 B-fragment order, nks = K/32:
// WtB[((ntile*nks + ks)*64 + lane)*8 + j] = bf16(Wt[ks*32+(lane>>4)*8+j][ntile*16+(lane&15)])
__global__ __launch_bounds__(256) void repack_b_k(const float* __restrict__ Wt,
                                                  short* __restrict__ WtB, int K) {
    int id = blockIdx.x * 256 + threadIdx.x;
    if (id >= K * 128) return;
    int k = id >> 7, h = id & 127;
    int nks = K >> 5;
    int ks = k >> 5, hi = (k >> 3) & 3, j = k & 7;
    int ntile = h >> 4, lc = h & 15;
    int lane = hi * 16 + lc;
    WtB[((ntile * nks + ks) * 64 + lane) * 8 + j] = (short)f2bf_bits(Wt[k * 128 + h]);
}

// GEMM1 weights: B(k,h) = w_rct[h][k] (h<128) / w_prd[h-128][k]; K=128, N=256
__global__ __launch_bounds__(256) void repack_w0_k(const float* __restrict__ w_rct,
                                                   const float* __restrict__ w_prd,
                                                   short* __restrict__ WtB) {
    int id = blockIdx.x * 256 + threadIdx.x;  // 32768
    int k = id >> 8, h = id & 255;
    float v = (h < 128) ? w_rct[h * 128 + k] : w_prd[(h - 128) * 128 + k];
    int ks = k >> 5, hi = (k >> 3) & 3, j = k & 7;
    int ntile = h >> 4, lc = h & 15;
    int lane = hi * 16 + lc;
    WtB[((ntile * 4 + ks) * 64 + lane) * 8 + j] = (short)f2bf_bits(v);
}

// ---------------------------------------------------------------------------
// dense MFMA GEMM: Out[n, 0:CPW*128] = bf16(A[n,0:128]) @ W (+bias)
// 512 threads = 8 waves; 64 rows; wave w -> col-tiles [w*CPW, w*CPW+CPW)
// In-place safe when Out aliases A (A fully staged to LDS before stores).
// ---------------------------------------------------------------------------
template <typename OT, int CPW, bool BIAS>
__global__ __launch_bounds__(512, 4) void gemm_dense_mfma(
    const float* A, const short* __restrict__ WtB,
    const float* __restrict__ biasv, OT* Out) {
    __shared__ alignas(16) short Asm[64][136];
    const int t = threadIdx.x, n0 = blockIdx.x * 64;
    const int lane = t & 63, w = t >> 6;
    const int lrow = lane & 15, lhi = lane >> 4;
    const int ldo = CPW * 128;

    // A stage: fp32 -> bf16 LDS
    {
        int row = t >> 3, g8 = t & 7;
        const float* p = A + (size_t)(n0 + row) * 128 + g8 * 16;
        u32* aw = (u32*)&Asm[0][0];
        int wb = row * 68 + g8 * 8;
#pragma unroll
        for (int c = 0; c < 2; ++c) {
            float4 a = *(const float4*)(p + c * 8);
            float4 b2 = *(const float4*)(p + c * 8 + 4);
            u32 pk0 = f2bf_bits(a.x) | (f2bf_bits(a.y) << 16);
            u32 pk1 = f2bf_bits(a.z) | (f2bf_bits(a.w) << 16);
            u32 pk2 = f2bf_bits(b2.x) | (f2bf_bits(b2.y) << 16);
            u32 pk3 = f2bf_bits(b2.z) | (f2bf_bits(b2.w) << 16);
            *(uint4*)&aw[wb + c * 4] = make_uint4(pk0, pk1, pk2, pk3);
        }
    }
    short8 bfrag[CPW][4];
#pragma unroll
    for (int c = 0; c < CPW; ++c)
#pragma unroll
        for (int ks = 0; ks < 4; ++ks)
            bfrag[c][ks] =
                *(const short8*)(WtB + (size_t)(((w * CPW + c) * 4 + ks) * 64 + lane) * 8);
    __syncthreads();

    f32x4 acc[4][CPW];
#pragma unroll
    for (int rt = 0; rt < 4; ++rt)
#pragma unroll
        for (int c = 0; c < CPW; ++c) acc[rt][c] = (f32x4){0.f, 0.f, 0.f, 0.f};
#pragma unroll
    for (int rt = 0; rt < 4; ++rt)
#pragma unroll
        for (int ks = 0; ks < 4; ++ks) {
            short8 af = *(const short8*)&Asm[rt * 16 + lrow][ks * 32 + lhi * 8];
#pragma unroll
            for (int c = 0; c < CPW; ++c) acc[rt][c] = MFMA16(af, bfrag[c][ks], acc[rt][c]);
        }
#pragma unroll
    for (int c = 0; c < CPW; ++c) {
        int col = (w * CPW + c) * 16 + lrow;
        float bb = BIAS ? biasv[col] : 0.f;
#pragma unroll
        for (int rt = 0; rt < 4; ++rt)
#pragma unroll
            for (int i = 0; i < 4; ++i) {
                int row = rt * 16 + lhi * 4 + i;
                storev(&Out[(size_t)(n0 + row) * ldo + col], acc[rt][c][i] + bb);
            }
    }
}

// ---------------------------------------------------------------------------
// MFMA gather GEMM, 512 threads = 8 waves, 64-row tile, edge-parity split.
// A[:,0:128]   = mean over CSR1[r] of src[b, idx, h2off==128 ? 0:128 : 0:128]
// A[:,128:256] = mean over CSR2[r] of src[b, idx, h2off + 0:128]
// Out = relu(A @ W(256x128) + base + m1*bm1 + m2*bm2), + BN stats
// ---------------------------------------------------------------------------
template <typename OT>
__global__ __launch_bounds__(512, 4) void gemm_gather_mfma(
    const __hip_bfloat16* __restrict__ src, int srcw, int h2off, int nsrc, int nbins,
    const int* __restrict__ off1, const int* __restrict__ idx1,
    const int* __restrict__ off2, const int* __restrict__ idx2,
    const short* __restrict__ WtB, const float* __restrict__ biasv,
    OT* __restrict__ Out, float* __restrict__ ssum, float* __restrict__ ssq) {
    __shared__ alignas(16) short Asm[64][264];
    __shared__ float m1s[64], m2s[64];
    const int t = threadIdx.x, n0 = blockIdx.x * 64;
    const int lane = t & 63, w = t >> 6;
    const int lrow = lane & 15, lhi = lane >> 4;

    // ---- gather: 8 threads/row = 4 col-chunks x 2 edge-parity ----
    {
        const int grow = t >> 3, sub = t & 7;
        const int gtc = sub & 3, epar = sub >> 2;
        const int n = n0 + grow;
        const int b = n / nbins;
        const int r = n - b * nbins;
#pragma unroll
        for (int half = 0; half < 2; ++half) {
            const int* off = half ? off2 : off1;
            const int* idx = half ? idx2 : idx1;
            int e0 = off[r], e1 = off[r + 1];
            float g[32];
#pragma unroll
            for (int j = 0; j < 32; ++j) g[j] = 0.f;
            const __hip_bfloat16* base =
                src + (size_t)b * nsrc * srcw + (half ? h2off : 0) + gtc * 32;
            for (int e = e0 + epar; e < e1; e += 2)
                acc32(base + (size_t)idx[e] * srcw, g);
            // combine the two parity partners (lane bit 2)
#pragma unroll
            for (int j = 0; j < 32; ++j) g[j] += __shfl_xor(g[j], 4);
            int cnt = e1 - e0;
            float sc = (cnt > 0) ? 1.f / (float)cnt : 0.f;
            if (sub == 0) (half ? m2s : m1s)[grow] = (cnt > 0) ? 1.f : 0.f;
            if (epar == 0) {
                u32* aw = (u32*)&Asm[0][0];
                int wb = grow * 132 + half * 64 + gtc * 16;
#pragma unroll
                for (int c = 0; c < 4; ++c) {
                    u32 pk[4];
#pragma unroll
                    for (int q = 0; q < 4; ++q)
                        pk[q] = f2bf_bits(g[c * 8 + q * 2] * sc) |
                                (f2bf_bits(g[c * 8 + q * 2 + 1] * sc) << 16);
                    *(uint4*)&aw[wb + c * 4] = make_uint4(pk[0], pk[1], pk[2], pk[3]);
                }
            }
        }
    }
    // ---- B fragments: wave w -> col-tile w (16 cols), 8 k-steps ----
    short8 bfrag[8];
#pragma unroll
    for (int ks = 0; ks < 8; ++ks)
        bfrag[ks] = *(const short8*)(WtB + (size_t)((w * 8 + ks) * 64 + lane) * 8);
    __syncthreads();

    f32x4 acc[4];
#pragma unroll
    for (int rt = 0; rt < 4; ++rt) acc[rt] = (f32x4){0.f, 0.f, 0.f, 0.f};
#pragma unroll
    for (int rt = 0; rt < 4; ++rt)
#pragma unroll
        for (int ks = 0; ks < 8; ++ks) {
            short8 af = *(const short8*)&Asm[rt * 16 + lrow][ks * 32 + lhi * 8];
            acc[rt] = MFMA16(af, bfrag[ks], acc[rt]);
        }

    // ---- epilogue ----
    const int col = w * 16 + lrow;
    float bb = biasv[col], bm1 = biasv[128 + col], bm2 = biasv[256 + col];
    float ps = 0.f, pq = 0.f;
#pragma unroll
    for (int rt = 0; rt < 4; ++rt)
#pragma unroll
        for (int i = 0; i < 4; ++i) {
            int row = rt * 16 + lhi * 4 + i;
            float v = acc[rt][i] + bb + m1s[row] * bm1 + m2s[row] * bm2;
            v = fmaxf(v, 0.f);
            ps += v;
            pq += v * v;
            storev(&Out[(size_t)(n0 + row) * 128 + col], v);
        }
    ps += __shfl_xor(ps, 16);
    ps += __shfl_xor(ps, 32);
    pq += __shfl_xor(pq, 16);
    pq += __shfl_xor(pq, 32);
    if (lhi == 0) {
        atomicAdd(&ssum[col], ps);
        atomicAdd(&ssq[col], pq);
    }
}

// ---------------------------------------------------------------------------
// launch
// ---------------------------------------------------------------------------
extern "C" void kernel_launch(void* const* d_in, const int* in_sizes, int n_in,
                              void* d_out, int out_size, void* d_ws, size_t ws_size,
                              hipStream_t stream) {
    const float* nodes = (const float*)d_in[0];
    const int* r2e = (const int*)d_in[1];
    const int* p2e = (const int*)d_in[2];
    const int* e2r = (const int*)d_in[3];
    const int* e2p = (const int*)d_in[4];
    const float* w_rct = (const float*)d_in[5];
    const float* b_rct = (const float*)d_in[6];
    const float* w_prd = (const float*)d_in[7];
    const float* b_prd = (const float*)d_in[8];
    const float* w_ra1 = (const float*)d_in[9];
    const float* b_ra1 = (const float*)d_in[10];
    const float* bn_r_g = (const float*)d_in[11];
    const float* bn_r_b = (const float*)d_in[12];
    const float* w_ra2 = (const float*)d_in[13];
    const float* b_ra2 = (const float*)d_in[14];
    const float* w_r2rct = (const float*)d_in[15];
    const float* b_r2rct = (const float*)d_in[16];
    const float* w_r2prd = (const float*)d_in[17];
    const float* b_r2prd = (const float*)d_in[18];
    const float* w_ma1 = (const float*)d_in[19];
    const float* b_ma1 = (const float*)d_in[20];
    const float* bn_m_g = (const float*)d_in[21];
    const float* bn_m_b = (const float*)d_in[22];
    const float* w_ma2 = (const float*)d_in[23];
    const float* b_ma2 = (const float*)d_in[24];

    char* ws = (char*)d_ws;
    size_t off = 0;
    auto alloc = [&](size_t bytes) -> char* {
        off = (off + 255) & ~(size_t)255;
        char* p = ws + off;
        off += bytes;
        return p;
    };

    const size_t H1B = (size_t)NB * NR * 128 * 2;  // 102.4 MB
    __hip_bfloat16* h1 = (__hip_bfloat16*)alloc(H1B);

    char* cntcur = alloc((size_t)8 * (NR + NR + NM + NM));
    int* cnt_r = (int*)cntcur;
    int* cnt_p = cnt_r + NR;
    int* cnt_er = cnt_p + NR;
    int* cnt_ep = cnt_er + NM;
    int* cur_r = cnt_ep + NM;
    int* cur_p = cur_r + NR;
    int* cur_er = cur_p + NR;
    int* cur_ep = cur_er + NM;
    int* off_r = (int*)alloc((NR + 1) * 4);
    int* off_p = (int*)alloc((NR + 1) * 4);
    int* off_er = (int*)alloc((NM + 1) * 4);
    int* off_ep = (int*)alloc((NM + 1) * 4);
    int* idx_r = (int*)alloc(NE * 4);
    int* idx_p = (int*)alloc(NE * 4);
    int* idx_er = (int*)alloc(NE * 4);
    int* idx_ep = (int*)alloc(NE * 4);

    float* statblk = (float*)alloc(4 * 128 * 4);
    float* sum1 = statblk;
    float* sq1 = statblk + 128;
    float* sum2 = statblk + 256;
    float* sq2 = statblk + 384;
    float* Wt1 = (float*)alloc(256 * 128 * 4);
    float* bias1 = (float*)alloc(3 * 128 * 4);
    float* W2p = (float*)alloc(128 * 128 * 4);
    float* b2p = (float*)alloc(128 * 4);
    float* Wc_r = (float*)alloc(128 * 128 * 4);
    float* bc_r = (float*)alloc(128 * 4);
    float* Wc_p = (float*)alloc(128 * 128 * 4);
    float* bc_p = (float*)alloc(128 * 4);
    float* Wt2 = (float*)alloc(256 * 128 * 4);
    float* bias2 = (float*)alloc(3 * 128 * 4);
    float* WoutT = (float*)alloc(128 * 128 * 4);
    float* b_out = (float*)alloc(128 * 4);
    short* WtB0 = (short*)alloc(128 * 256 * 2);
    short* WtB1 = (short*)alloc(256 * 128 * 2);
    short* WtB2 = (short*)alloc(256 * 128 * 2);
    short* WtBo = (short*)alloc(128 * 128 * 2);
    (void)ws_size;

    // hid (B,M,256 bf16) and h2 (B,M,128 f32) both live in d_out (81.92 MB)
    __hip_bfloat16* hid = (__hip_bfloat16*)d_out;
    float* h2 = (float*)d_out;

    hipMemsetAsync(cntcur, 0, (size_t)8 * (NR + NR + NM + NM), stream);
    hipMemsetAsync(statblk, 0, 4 * 128 * 4, stream);

    // ---- CSR build ----
    const int EB = (NE + 255) / 256;
    hist_k<<<EB, 256, 0, stream>>>(r2e + NE, cnt_r, NE);
    hist_k<<<EB, 256, 0, stream>>>(p2e + NE, cnt_p, NE);
    hist_k<<<EB, 256, 0, stream>>>(e2r + NE, cnt_er, NE);
    hist_k<<<EB, 256, 0, stream>>>(e2p + NE, cnt_ep, NE);
    scan4_k<<<4, 1024, 0, stream>>>(cnt_r, off_r, NR, cnt_p, off_p, NR,
                                    cnt_er, off_er, NM, cnt_ep, off_ep, NM);
    fill_k<<<EB, 256, 0, stream>>>(r2e, off_r, cur_r, idx_r, NE);
    fill_k<<<EB, 256, 0, stream>>>(p2e, off_p, cur_p, idx_p, NE);
    fill_k<<<EB, 256, 0, stream>>>(e2r, off_er, cur_er, idx_er, NE);
    fill_k<<<EB, 256, 0, stream>>>(e2p, off_ep, cur_ep, idx_ep, NE);

    // ---- GEMM1 (MFMA, fused halves): hid = bf16(nodes) @ [w_rct^T | w_prd^T] ----
    repack_w0_k<<<128, 256, 0, stream>>>(w_rct, w_prd, WtB0);
    gemm_dense_mfma<__hip_bfloat16, 2, false><<<(NB * NM) / 64, 512, 0, stream>>>(
        nodes, WtB0, nullptr, hid);

    // ---- GEMM2 (MFMA gather): h1 = relu(gather(hid)@Wt1 + biases) + BN1 stats ----
    prep_w1_k<<<256, 128, 0, stream>>>(w_ra1, b_ra1, b_rct, b_prd, Wt1, bias1);
    repack_b_k<<<128, 256, 0, stream>>>(Wt1, WtB1, 256);
    gemm_gather_mfma<__hip_bfloat16><<<(NB * NR) / 64, 512, 0, stream>>>(
        hid, 256, 128, NM, NR, off_r, idx_r, off_p, idx_p, WtB1, bias1, h1, sum1, sq1);

    // ---- fold BN1 -> w_ra2 -> w_r2rct/w_r2prd -> w_ma1 ----
    prep2a_k<<<1, 128, 0, stream>>>(sum1, sq1, bn_r_g, bn_r_b, w_ra2, b_ra2,
                                    (float)((size_t)NB * NR), W2p, b2p);
    prep2b_k<<<256, 128, 0, stream>>>(w_r2rct, b_r2rct, w_r2prd, b_r2prd, W2p, b2p,
                                      Wc_r, bc_r, Wc_p, bc_p);
    prep1_k<<<256, 128, 0, stream>>>(Wc_r, Wc_p, w_ma1, bc_r, bc_p, b_ma1, Wt2, bias2);
    repack_b_k<<<128, 256, 0, stream>>>(Wt2, WtB2, 256);

    // ---- GEMM4 (MFMA gather): h2 = relu(gather(h1)@Wt2 + biases) -> d_out ----
    gemm_gather_mfma<float><<<(NB * NM) / 64, 512, 0, stream>>>(
        h1, 128, 0, NR, NM, off_er, idx_er, off_ep, idx_ep, WtB2, bias2, h2, sum2, sq2);

    // ---- fold BN2; GEMM5 (MFMA) in-place on d_out ----
    prep3_k<<<1, 128, 0, stream>>>(sum2, sq2, bn_m_g, bn_m_b, w_ma2, b_ma2,
                                   (float)((size_t)NB * NM), WoutT, b_out);
    repack_b_k<<<64, 256, 0, stream>>>(WoutT, WtBo, 128);
    gemm_dense_mfma<float, 1, true><<<(NB * NM) / 64, 512, 0, stream>>>(
        h2, WtBo, b_out, (float*)d_out);
}

// Round 5
// 497.005 us; speedup vs baseline: 2.1578x; 1.0124x over previous
//
#include <hip/hip_runtime.h>
#include <hip/hip_bf16.h>

#define NB 8
#define NM 20000
#define NR 50000
#define NE 100000
#define BN_EPS 1e-5f

typedef unsigned int u32;

using short8 = __attribute__((ext_vector_type(8))) short;  // 8 bf16
using f32x4 = __attribute__((ext_vector_type(4))) float;

#define MFMA16(a, b, c) __builtin_amdgcn_mfma_f32_16x16x32_bf16(a, b, c, 0, 0, 0)

__device__ inline u32 f2bf_bits(float f) {
    u32 x = __float_as_uint(f);
    return (x + 0x7fffu + ((x >> 16) & 1u)) >> 16;
}
__device__ inline void storev(float* p, float v) { *p = v; }
__device__ inline void storev(__hip_bfloat16* p, float v) {
    *(unsigned short*)p = (unsigned short)f2bf_bits(v);
}

// accumulate 16 bf16 cols (32B) into fp32
__device__ inline void acc16(const __hip_bfloat16* p, float* g) {
    uint4 q0 = *(const uint4*)p;
    uint4 q1 = *(const uint4*)(p + 8);
    u32 ww[8] = {q0.x, q0.y, q0.z, q0.w, q1.x, q1.y, q1.z, q1.w};
#pragma unroll
    for (int q = 0; q < 8; ++q) {
        g[q * 2] += __uint_as_float(ww[q] << 16);
        g[q * 2 + 1] += __uint_as_float(ww[q] & 0xFFFF0000u);
    }
}

// ---------------------------------------------------------------------------
// CSR build
// ---------------------------------------------------------------------------
__global__ __launch_bounds__(256) void hist_k(const int* __restrict__ dst,
                                              int* __restrict__ cnt, int n) {
    int i = blockIdx.x * 256 + threadIdx.x;
    if (i < n) atomicAdd(&cnt[dst[i]], 1);
}

__global__ __launch_bounds__(1024) void scan4_k(
    const int* c0, int* o0, int n0, const int* c1, int* o1, int n1,
    const int* c2, int* o2, int n2, const int* c3, int* o3, int n3) {
    const int* c; int* o; int n;
    if (blockIdx.x == 0) { c = c0; o = o0; n = n0; }
    else if (blockIdx.x == 1) { c = c1; o = o1; n = n1; }
    else if (blockIdx.x == 2) { c = c2; o = o2; n = n2; }
    else { c = c3; o = o3; n = n3; }
    __shared__ int wsum[16];
    __shared__ int carry_s;
    int t = threadIdx.x, lane = t & 63, w = t >> 6;
    if (t == 0) carry_s = 0;
    __syncthreads();
    for (int base = 0; base < n; base += 1024) {
        int i = base + t;
        int x = (i < n) ? c[i] : 0;
#pragma unroll
        for (int s = 1; s < 64; s <<= 1) {
            int y = __shfl_up(x, s);
            if (lane >= s) x += y;
        }
        if (lane == 63) wsum[w] = x;
        __syncthreads();
        if (w == 0) {
            int ws = (lane < 16) ? wsum[lane] : 0;
#pragma unroll
            for (int s = 1; s < 16; s <<= 1) {
                int y = __shfl_up(ws, s);
                if (lane >= s) ws += y;
            }
            if (lane < 16) wsum[lane] = ws;
        }
        __syncthreads();
        int wbase = (w > 0) ? wsum[w - 1] : 0;
        int incl = x + wbase + carry_s;
        if (i < n) o[i + 1] = incl;
        __syncthreads();
        if (t == 1023) carry_s = incl;
        __syncthreads();
    }
    if (t == 0) o[0] = 0;
}

__global__ __launch_bounds__(256) void fill_k(const int* __restrict__ edges,
                                              const int* __restrict__ off,
                                              int* __restrict__ cur,
                                              int* __restrict__ idx, int n) {
    int i = blockIdx.x * 256 + threadIdx.x;
    if (i < n) {
        int d = edges[n + i];
        int p = atomicAdd(&cur[d], 1);
        idx[off[d] + p] = edges[i];
    }
}

// ---------------------------------------------------------------------------
// weight preps (unchanged, proven)
// ---------------------------------------------------------------------------
__global__ __launch_bounds__(128) void prep_w1_k(const float* __restrict__ w_ra1,
                                                 const float* __restrict__ b_ra1,
                                                 const float* __restrict__ b_rct,
                                                 const float* __restrict__ b_prd,
                                                 float* __restrict__ Wt1,
                                                 float* __restrict__ bias1) {
    int k = blockIdx.x, h = threadIdx.x;
    Wt1[k * 128 + h] = w_ra1[h * 128 + (k & 127)];
    if (k == 0) {
        float s1 = 0.f, s2 = 0.f;
        for (int j = 0; j < 128; ++j) {
            float w = w_ra1[h * 128 + j];
            s1 = fmaf(w, b_rct[j], s1);
            s2 = fmaf(w, b_prd[j], s2);
        }
        bias1[h] = b_ra1[h];
        bias1[128 + h] = s1;
        bias1[256 + h] = s2;
    }
}

__global__ __launch_bounds__(128) void prep2a_k(const float* __restrict__ ssum,
                                                const float* __restrict__ ssq,
                                                const float* __restrict__ g,
                                                const float* __restrict__ beta,
                                                const float* __restrict__ w_ra2,
                                                const float* __restrict__ b_ra2,
                                                float Nf, float* __restrict__ W2p,
                                                float* __restrict__ b2p) {
    int h = threadIdx.x;
    __shared__ float t1[128];
    float mean = ssum[h] / Nf;
    float var = ssq[h] / Nf - mean * mean;
    float sv = g[h] * rsqrtf(var + BN_EPS);
    t1[h] = beta[h] - mean * sv;
    for (int r = 0; r < 128; ++r) W2p[r * 128 + h] = w_ra2[r * 128 + h] * sv;
    __syncthreads();
    float sb = 0.f;
    for (int d = 0; d < 128; ++d) sb = fmaf(t1[d], w_ra2[h * 128 + d], sb);
    b2p[h] = sb + b_ra2[h];
}

__global__ __launch_bounds__(128) void prep2b_k(const float* __restrict__ w_r2rct,
                                                const float* __restrict__ b_r2rct,
                                                const float* __restrict__ w_r2prd,
                                                const float* __restrict__ b_r2prd,
                                                const float* __restrict__ W2p,
                                                const float* __restrict__ b2p,
                                                float* __restrict__ Wc_r,
                                                float* __restrict__ bc_r,
                                                float* __restrict__ Wc_p,
                                                float* __restrict__ bc_p) {
    int blk = blockIdx.x;
    int d = threadIdx.x;
    int h = blk & 127;
    bool second = blk >= 128;
    const float* w = second ? w_r2prd : w_r2rct;
    const float* bsrc = second ? b_r2prd : b_r2rct;
    float* Wc = second ? Wc_p : Wc_r;
    float* bc = second ? bc_p : bc_r;
    __shared__ float rowv[128];
    __shared__ float red[128];
    rowv[d] = w[h * 128 + d];
    __syncthreads();
    float s = 0.f;
#pragma unroll 4
    for (int j = 0; j < 128; ++j) s = fmaf(rowv[j], W2p[j * 128 + d], s);
    Wc[h * 128 + d] = s;
    red[d] = rowv[d] * b2p[d];
    __syncthreads();
    for (int off = 64; off > 0; off >>= 1) {
        if (d < off) red[d] += red[d + off];
        __syncthreads();
    }
    if (d == 0) bc[h] = red[0] + bsrc[h];
}

__global__ __launch_bounds__(128) void prep1_k(const float* __restrict__ w_s1,
                                               const float* __restrict__ w_s2,
                                               const float* __restrict__ w_big,
                                               const float* __restrict__ b_s1,
                                               const float* __restrict__ b_s2,
                                               const float* __restrict__ b_big,
                                               float* __restrict__ Wt,
                                               float* __restrict__ bias) {
    int k = blockIdx.x;
    int h = threadIdx.x;
    __shared__ float col[128];
    const float* wsrc = (k < 128) ? w_s1 : w_s2;
    int kk = k & 127;
    col[h] = wsrc[h * 128 + kk];
    __syncthreads();
    float s = 0.f;
#pragma unroll 4
    for (int j = 0; j < 128; ++j) s = fmaf(w_big[h * 128 + j], col[j], s);
    Wt[k * 128 + h] = s;
    if (k == 0) {
        float sb1 = 0.f, sb2 = 0.f;
        for (int j = 0; j < 128; ++j) {
            sb1 = fmaf(w_big[h * 128 + j], b_s1[j], sb1);
            sb2 = fmaf(w_big[h * 128 + j], b_s2[j], sb2);
        }
        bias[h] = b_big[h];
        bias[128 + h] = sb1;
        bias[256 + h] = sb2;
    }
}

__global__ __launch_bounds__(128) void prep3_k(const float* __restrict__ ssum,
                                               const float* __restrict__ ssq,
                                               const float* __restrict__ g,
                                               const float* __restrict__ beta,
                                               const float* __restrict__ w_ma2,
                                               const float* __restrict__ b_ma2,
                                               float Nf, float* __restrict__ WoutT,
                                               float* __restrict__ b_out) {
    int h = threadIdx.x;
    __shared__ float s2[128], t2[128];
    float mean = ssum[h] / Nf;
    float var = ssq[h] / Nf - mean * mean;
    float sv = g[h] * rsqrtf(var + BN_EPS);
    s2[h] = sv;
    t2[h] = beta[h] - mean * sv;
    __syncthreads();
    for (int k = 0; k < 128; ++k) WoutT[k * 128 + h] = w_ma2[h * 128 + k] * s2[k];
    float sb = 0.f;
    for (int k = 0; k < 128; ++k) sb = fmaf(t2[k], w_ma2[h * 128 + k], sb);
    b_out[h] = sb + b_ma2[h];
}

// Repack k-major Wt (K x 128 fp32) to bf16 B-fragment order, nks = K/32
__global__ __launch_bounds__(256) void repack_b_k(const float* __restrict__ Wt,
                                                  short* __restrict__ WtB, int K) {
    int id = blockIdx.x * 256 + threadIdx.x;
    if (id >= K * 128) return;
    int k = id >> 7, h = id & 127;
    int nks = K >> 5;
    int ks = k >> 5, hi = (k >> 3) & 3, j = k & 7;
    int ntile = h >> 4, lc = h & 15;
    int lane = hi * 16 + lc;
    WtB[((ntile * nks + ks) * 64 + lane) * 8 + j] = (short)f2bf_bits(Wt[k * 128 + h]);
}

// GEMM1 weights: B(k,h) = w_rct[h][k] (h<128) / w_prd[h-128][k]; K=128, N=256
__global__ __launch_bounds__(256) void repack_w0_k(const float* __restrict__ w_rct,
                                                   const float* __restrict__ w_prd,
                                                   short* __restrict__ WtB) {
    int id = blockIdx.x * 256 + threadIdx.x;  // 32768
    int k = id >> 8, h = id & 255;
    float v = (h < 128) ? w_rct[h * 128 + k] : w_prd[(h - 128) * 128 + k];
    int ks = k >> 5, hi = (k >> 3) & 3, j = k & 7;
    int ntile = h >> 4, lc = h & 15;
    int lane = hi * 16 + lc;
    WtB[((ntile * 4 + ks) * 64 + lane) * 8 + j] = (short)f2bf_bits(v);
}

// ---------------------------------------------------------------------------
// dense MFMA GEMM: Out[n, 0:CPW*128] = bf16(A[arow(n),0:128]) @ W (+bias)
// APERM: A row for tile-row `row` is (row&7)*permN + blockIdx*8 + (row>>3)
//        (reads batch-major A while writing node-major Out)
// In-place safe when Out aliases A and APERM=false (A staged before stores).
// ---------------------------------------------------------------------------
template <typename OT, int CPW, bool BIAS, bool APERM>
__global__ __launch_bounds__(512, 4) void gemm_dense_mfma(
    const float* A, const short* __restrict__ WtB,
    const float* __restrict__ biasv, OT* Out, int permN) {
    __shared__ alignas(16) short Asm[64][136];
    const int t = threadIdx.x, n0 = blockIdx.x * 64;
    const int lane = t & 63, w = t >> 6;
    const int lrow = lane & 15, lhi = lane >> 4;
    const int ldo = CPW * 128;

    // A stage: fp32 -> bf16 LDS
    {
        int row = t >> 3, g8 = t & 7;
        size_t arow = APERM ? ((size_t)(row & 7) * permN + (blockIdx.x * 8 + (row >> 3)))
                            : (size_t)(n0 + row);
        const float* p = A + arow * 128 + g8 * 16;
        u32* aw = (u32*)&Asm[0][0];
        int wb = row * 68 + g8 * 8;
#pragma unroll
        for (int c = 0; c < 2; ++c) {
            float4 a = *(const float4*)(p + c * 8);
            float4 b2 = *(const float4*)(p + c * 8 + 4);
            u32 pk0 = f2bf_bits(a.x) | (f2bf_bits(a.y) << 16);
            u32 pk1 = f2bf_bits(a.z) | (f2bf_bits(a.w) << 16);
            u32 pk2 = f2bf_bits(b2.x) | (f2bf_bits(b2.y) << 16);
            u32 pk3 = f2bf_bits(b2.z) | (f2bf_bits(b2.w) << 16);
            *(uint4*)&aw[wb + c * 4] = make_uint4(pk0, pk1, pk2, pk3);
        }
    }
    short8 bfrag[CPW][4];
#pragma unroll
    for (int c = 0; c < CPW; ++c)
#pragma unroll
        for (int ks = 0; ks < 4; ++ks)
            bfrag[c][ks] =
                *(const short8*)(WtB + (size_t)(((w * CPW + c) * 4 + ks) * 64 + lane) * 8);
    __syncthreads();

    f32x4 acc[4][CPW];
#pragma unroll
    for (int rt = 0; rt < 4; ++rt)
#pragma unroll
        for (int c = 0; c < CPW; ++c) acc[rt][c] = (f32x4){0.f, 0.f, 0.f, 0.f};
#pragma unroll
    for (int rt = 0; rt < 4; ++rt)
#pragma unroll
        for (int ks = 0; ks < 4; ++ks) {
            short8 af = *(const short8*)&Asm[rt * 16 + lrow][ks * 32 + lhi * 8];
#pragma unroll
            for (int c = 0; c < CPW; ++c) acc[rt][c] = MFMA16(af, bfrag[c][ks], acc[rt][c]);
        }
#pragma unroll
    for (int c = 0; c < CPW; ++c) {
        int col = (w * CPW + c) * 16 + lrow;
        float bb = BIAS ? biasv[col] : 0.f;
#pragma unroll
        for (int rt = 0; rt < 4; ++rt)
#pragma unroll
            for (int i = 0; i < 4; ++i) {
                int row = rt * 16 + lhi * 4 + i;
                storev(&Out[(size_t)(n0 + row) * ldo + col], acc[rt][c][i] + bb);
            }
    }
}

// ---------------------------------------------------------------------------
// MFMA gather GEMM, node-major src [nsrc, B=8, SRCW] bf16.
// Block = 8 bins x 8 batches = 64 rows; wave w owns bin (blockIdx*8+w):
//   lane: batch = lane>>3, ck = lane&7 (16 cols). Edge idx/off are wave-uniform
//   (scalar loads); per edge the wave reads 8x256B (or 8x512B) bursts.
// A[:,0:128] = mean over CSR1[bin]; A[:,128:256] = mean over CSR2[bin].
// Out = relu(A @ W(256x128) + base + m1*bm1 + m2*bm2), + BN stats.
// PERM: write Out row (batch*permN + bin) (un-permute to batch-major).
// ---------------------------------------------------------------------------
template <typename OT, int SRCW, int H2OFF, bool PERM>
__global__ __launch_bounds__(512, 4) void gemm_gather_mfma(
    const __hip_bfloat16* __restrict__ src,
    const int* __restrict__ off1, const int* __restrict__ idx1,
    const int* __restrict__ off2, const int* __restrict__ idx2,
    const short* __restrict__ WtB, const float* __restrict__ biasv,
    OT* __restrict__ Out, int permN, float* __restrict__ ssum,
    float* __restrict__ ssq) {
    __shared__ alignas(16) short Asm[64][264];
    __shared__ float m1s[64], m2s[64];
    const int t = threadIdx.x;
    const int lane = t & 63;
    const int w = __builtin_amdgcn_readfirstlane(t >> 6);
    const int lrow = lane & 15, lhi = lane >> 4;
    const int bin0 = blockIdx.x * 8;

    // B fragments early (complete during gather latency)
    short8 bfrag[8];
#pragma unroll
    for (int ks = 0; ks < 8; ++ks)
        bfrag[ks] = *(const short8*)(WtB + (size_t)((w * 8 + ks) * 64 + lane) * 8);

    // ---- gather: wave w -> bin rb; lane covers (batch, 16-col chunk) ----
    {
        const int rb = bin0 + w;
        const int batch = lane >> 3, ck = lane & 7;
        const int arow = w * 8 + batch;
        const __hip_bfloat16* lsrc = src + batch * SRCW + ck * 16;
#pragma unroll
        for (int half = 0; half < 2; ++half) {
            const int* offp = half ? off2 : off1;
            const int* idxp = half ? idx2 : idx1;
            int e0 = offp[rb], e1 = offp[rb + 1];
            float g[16];
#pragma unroll
            for (int j = 0; j < 16; ++j) g[j] = 0.f;
            const __hip_bfloat16* base = lsrc + (half ? H2OFF : 0);
            int e = e0;
            for (; e + 2 <= e1; e += 2) {
                int i0 = idxp[e], i1 = idxp[e + 1];
                acc16(base + (size_t)i0 * (8 * SRCW), g);
                acc16(base + (size_t)i1 * (8 * SRCW), g);
            }
            if (e < e1) acc16(base + (size_t)idxp[e] * (8 * SRCW), g);
            int cnt = e1 - e0;
            float sc = (cnt > 0) ? 1.f / (float)cnt : 0.f;
            if (ck == 0) (half ? m2s : m1s)[arow] = (cnt > 0) ? 1.f : 0.f;
            u32* aw = (u32*)&Asm[0][0];
            int wb = arow * 132 + half * 64 + ck * 8;
            u32 pk[8];
#pragma unroll
            for (int q = 0; q < 8; ++q)
                pk[q] = f2bf_bits(g[q * 2] * sc) | (f2bf_bits(g[q * 2 + 1] * sc) << 16);
            *(uint4*)&aw[wb] = make_uint4(pk[0], pk[1], pk[2], pk[3]);
            *(uint4*)&aw[wb + 4] = make_uint4(pk[4], pk[5], pk[6], pk[7]);
        }
    }
    __syncthreads();

    // ---- MFMA: 4 row-tiles x 8 k-steps; wave w -> col-tile w ----
    f32x4 acc[4];
#pragma unroll
    for (int rt = 0; rt < 4; ++rt) acc[rt] = (f32x4){0.f, 0.f, 0.f, 0.f};
#pragma unroll
    for (int rt = 0; rt < 4; ++rt)
#pragma unroll
        for (int ks = 0; ks < 8; ++ks) {
            short8 af = *(const short8*)&Asm[rt * 16 + lrow][ks * 32 + lhi * 8];
            acc[rt] = MFMA16(af, bfrag[ks], acc[rt]);
        }

    // ---- epilogue ----
    const int col = w * 16 + lrow;
    float bb = biasv[col], bm1 = biasv[128 + col], bm2 = biasv[256 + col];
    float ps = 0.f, pq = 0.f;
#pragma unroll
    for (int rt = 0; rt < 4; ++rt)
#pragma unroll
        for (int i = 0; i < 4; ++i) {
            int row = rt * 16 + lhi * 4 + i;
            float v = acc[rt][i] + bb + m1s[row] * bm1 + m2s[row] * bm2;
            v = fmaxf(v, 0.f);
            ps += v;
            pq += v * v;
            size_t orow = PERM ? ((size_t)(row & 7) * permN + (bin0 + (row >> 3)))
                               : (size_t)(blockIdx.x * 64 + row);
            storev(&Out[orow * 128 + col], v);
        }
    ps += __shfl_xor(ps, 16);
    ps += __shfl_xor(ps, 32);
    pq += __shfl_xor(pq, 16);
    pq += __shfl_xor(pq, 32);
    if (lhi == 0) {
        atomicAdd(&ssum[col], ps);
        atomicAdd(&ssq[col], pq);
    }
}

// ---------------------------------------------------------------------------
// launch
// ---------------------------------------------------------------------------
extern "C" void kernel_launch(void* const* d_in, const int* in_sizes, int n_in,
                              void* d_out, int out_size, void* d_ws, size_t ws_size,
                              hipStream_t stream) {
    const float* nodes = (const float*)d_in[0];
    const int* r2e = (const int*)d_in[1];
    const int* p2e = (const int*)d_in[2];
    const int* e2r = (const int*)d_in[3];
    const int* e2p = (const int*)d_in[4];
    const float* w_rct = (const float*)d_in[5];
    const float* b_rct = (const float*)d_in[6];
    const float* w_prd = (const float*)d_in[7];
    const float* b_prd = (const float*)d_in[8];
    const float* w_ra1 = (const float*)d_in[9];
    const float* b_ra1 = (const float*)d_in[10];
    const float* bn_r_g = (const float*)d_in[11];
    const float* bn_r_b = (const float*)d_in[12];
    const float* w_ra2 = (const float*)d_in[13];
    const float* b_ra2 = (const float*)d_in[14];
    const float* w_r2rct = (const float*)d_in[15];
    const float* b_r2rct = (const float*)d_in[16];
    const float* w_r2prd = (const float*)d_in[17];
    const float* b_r2prd = (const float*)d_in[18];
    const float* w_ma1 = (const float*)d_in[19];
    const float* b_ma1 = (const float*)d_in[20];
    const float* bn_m_g = (const float*)d_in[21];
    const float* bn_m_b = (const float*)d_in[22];
    const float* w_ma2 = (const float*)d_in[23];
    const float* b_ma2 = (const float*)d_in[24];

    char* ws = (char*)d_ws;
    size_t off = 0;
    auto alloc = [&](size_t bytes) -> char* {
        off = (off + 255) & ~(size_t)255;
        char* p = ws + off;
        off += bytes;
        return p;
    };

    const size_t H1B = (size_t)NR * NB * 128 * 2;  // 102.4 MB, node-major [R,B,128]
    __hip_bfloat16* h1 = (__hip_bfloat16*)alloc(H1B);

    char* cntcur = alloc((size_t)8 * (NR + NR + NM + NM));
    int* cnt_r = (int*)cntcur;
    int* cnt_p = cnt_r + NR;
    int* cnt_er = cnt_p + NR;
    int* cnt_ep = cnt_er + NM;
    int* cur_r = cnt_ep + NM;
    int* cur_p = cur_r + NR;
    int* cur_er = cur_p + NR;
    int* cur_ep = cur_er + NM;
    int* off_r = (int*)alloc((NR + 1) * 4);
    int* off_p = (int*)alloc((NR + 1) * 4);
    int* off_er = (int*)alloc((NM + 1) * 4);
    int* off_ep = (int*)alloc((NM + 1) * 4);
    int* idx_r = (int*)alloc(NE * 4);
    int* idx_p = (int*)alloc(NE * 4);
    int* idx_er = (int*)alloc(NE * 4);
    int* idx_ep = (int*)alloc(NE * 4);

    float* statblk = (float*)alloc(4 * 128 * 4);
    float* sum1 = statblk;
    float* sq1 = statblk + 128;
    float* sum2 = statblk + 256;
    float* sq2 = statblk + 384;
    float* Wt1 = (float*)alloc(256 * 128 * 4);
    float* bias1 = (float*)alloc(3 * 128 * 4);
    float* W2p = (float*)alloc(128 * 128 * 4);
    float* b2p = (float*)alloc(128 * 4);
    float* Wc_r = (float*)alloc(128 * 128 * 4);
    float* bc_r = (float*)alloc(128 * 4);
    float* Wc_p = (float*)alloc(128 * 128 * 4);
    float* bc_p = (float*)alloc(128 * 4);
    float* Wt2 = (float*)alloc(256 * 128 * 4);
    float* bias2 = (float*)alloc(3 * 128 * 4);
    float* WoutT = (float*)alloc(128 * 128 * 4);
    float* b_out = (float*)alloc(128 * 4);
    short* WtB0 = (short*)alloc(128 * 256 * 2);
    short* WtB1 = (short*)alloc(256 * 128 * 2);
    short* WtB2 = (short*)alloc(256 * 128 * 2);
    short* WtBo = (short*)alloc(128 * 128 * 2);
    (void)ws_size;

    // hid [M,B,256] bf16 and h2 [B,M,128] f32 both live in d_out (81.92 MB)
    __hip_bfloat16* hid = (__hip_bfloat16*)d_out;
    float* h2 = (float*)d_out;

    hipMemsetAsync(cntcur, 0, (size_t)8 * (NR + NR + NM + NM), stream);
    hipMemsetAsync(statblk, 0, 4 * 128 * 4, stream);

    // ---- CSR build ----
    const int EB = (NE + 255) / 256;
    hist_k<<<EB, 256, 0, stream>>>(r2e + NE, cnt_r, NE);
    hist_k<<<EB, 256, 0, stream>>>(p2e + NE, cnt_p, NE);
    hist_k<<<EB, 256, 0, stream>>>(e2r + NE, cnt_er, NE);
    hist_k<<<EB, 256, 0, stream>>>(e2p + NE, cnt_ep, NE);
    scan4_k<<<4, 1024, 0, stream>>>(cnt_r, off_r, NR, cnt_p, off_p, NR,
                                    cnt_er, off_er, NM, cnt_ep, off_ep, NM);
    fill_k<<<EB, 256, 0, stream>>>(r2e, off_r, cur_r, idx_r, NE);
    fill_k<<<EB, 256, 0, stream>>>(p2e, off_p, cur_p, idx_p, NE);
    fill_k<<<EB, 256, 0, stream>>>(e2r, off_er, cur_er, idx_er, NE);
    fill_k<<<EB, 256, 0, stream>>>(e2p, off_ep, cur_ep, idx_ep, NE);

    // ---- GEMM1: hid[m,b,:] = bf16(nodes[b,m,:]) @ [w_rct^T | w_prd^T] ----
    repack_w0_k<<<128, 256, 0, stream>>>(w_rct, w_prd, WtB0);
    gemm_dense_mfma<__hip_bfloat16, 2, false, true><<<(NB * NM) / 64, 512, 0, stream>>>(
        nodes, WtB0, nullptr, hid, NM);

    // ---- GEMM2 (gather): h1[r,b,:] = relu(gather(hid)@Wt1 + biases) + BN1 stats ----
    prep_w1_k<<<256, 128, 0, stream>>>(w_ra1, b_ra1, b_rct, b_prd, Wt1, bias1);
    repack_b_k<<<128, 256, 0, stream>>>(Wt1, WtB1, 256);
    gemm_gather_mfma<__hip_bfloat16, 256, 128, false><<<NR / 8, 512, 0, stream>>>(
        hid, off_r, idx_r, off_p, idx_p, WtB1, bias1, h1, 0, sum1, sq1);

    // ---- fold BN1 -> w_ra2 -> w_r2rct/w_r2prd -> w_ma1 ----
    prep2a_k<<<1, 128, 0, stream>>>(sum1, sq1, bn_r_g, bn_r_b, w_ra2, b_ra2,
                                    (float)((size_t)NB * NR), W2p, b2p);
    prep2b_k<<<256, 128, 0, stream>>>(w_r2rct, b_r2rct, w_r2prd, b_r2prd, W2p, b2p,
                                      Wc_r, bc_r, Wc_p, bc_p);
    prep1_k<<<256, 128, 0, stream>>>(Wc_r, Wc_p, w_ma1, bc_r, bc_p, b_ma1, Wt2, bias2);
    repack_b_k<<<128, 256, 0, stream>>>(Wt2, WtB2, 256);

    // ---- GEMM4 (gather): h2[b,m,:] = relu(gather(h1)@Wt2 + biases) -> d_out ----
    gemm_gather_mfma<float, 128, 0, true><<<NM / 8, 512, 0, stream>>>(
        h1, off_er, idx_er, off_ep, idx_ep, WtB2, bias2, h2, NM, sum2, sq2);

    // ---- fold BN2; GEMM5 (MFMA) in-place on d_out ----
    prep3_k<<<1, 128, 0, stream>>>(sum2, sq2, bn_m_g, bn_m_b, w_ma2, b_ma2,
                                   (float)((size_t)NB * NM), WoutT, b_out);
    repack_b_k<<<64, 256, 0, stream>>>(WoutT, WtBo, 128);
    gemm_dense_mfma<float, 1, true, false><<<(NB * NM) / 64, 512, 0, stream>>>(
        h2, WtBo, b_out, (float*)d_out, 0);
}

// Round 6
// 415.658 us; speedup vs baseline: 2.5801x; 1.1957x over previous
//
#include <hip/hip_runtime.h>
#include <hip/hip_bf16.h>

#define NB 8
#define NM 20000
#define NR 50000
#define NE 100000
#define BN_EPS 1e-5f

typedef unsigned int u32;

using short8 = __attribute__((ext_vector_type(8))) short;  // 8 bf16
using f32x4 = __attribute__((ext_vector_type(4))) float;

#define MFMA16(a, b, c) __builtin_amdgcn_mfma_f32_16x16x32_bf16(a, b, c, 0, 0, 0)

__device__ inline u32 f2bf_bits(float f) {
    u32 x = __float_as_uint(f);
    return (x + 0x7fffu + ((x >> 16) & 1u)) >> 16;
}
__device__ inline void storev(float* p, float v) { *p = v; }
__device__ inline void storev(__hip_bfloat16* p, float v) {
    *(unsigned short*)p = (unsigned short)f2bf_bits(v);
}

// accumulate 16 bf16 cols (32B) into fp32
__device__ inline void acc16(const __hip_bfloat16* p, float* g) {
    uint4 q0 = *(const uint4*)p;
    uint4 q1 = *(const uint4*)(p + 8);
    u32 ww[8] = {q0.x, q0.y, q0.z, q0.w, q1.x, q1.y, q1.z, q1.w};
#pragma unroll
    for (int q = 0; q < 8; ++q) {
        g[q * 2] += __uint_as_float(ww[q] << 16);
        g[q * 2 + 1] += __uint_as_float(ww[q] & 0xFFFF0000u);
    }
}

// ---------------------------------------------------------------------------
// CSR build
// ---------------------------------------------------------------------------
__global__ __launch_bounds__(256) void hist_k(const int* __restrict__ dst,
                                              int* __restrict__ cnt, int n) {
    int i = blockIdx.x * 256 + threadIdx.x;
    if (i < n) atomicAdd(&cnt[dst[i]], 1);
}

__global__ __launch_bounds__(1024) void scan4_k(
    const int* c0, int* o0, int n0, const int* c1, int* o1, int n1,
    const int* c2, int* o2, int n2, const int* c3, int* o3, int n3) {
    const int* c; int* o; int n;
    if (blockIdx.x == 0) { c = c0; o = o0; n = n0; }
    else if (blockIdx.x == 1) { c = c1; o = o1; n = n1; }
    else if (blockIdx.x == 2) { c = c2; o = o2; n = n2; }
    else { c = c3; o = o3; n = n3; }
    __shared__ int wsum[16];
    __shared__ int carry_s;
    int t = threadIdx.x, lane = t & 63, w = t >> 6;
    if (t == 0) carry_s = 0;
    __syncthreads();
    for (int base = 0; base < n; base += 1024) {
        int i = base + t;
        int x = (i < n) ? c[i] : 0;
#pragma unroll
        for (int s = 1; s < 64; s <<= 1) {
            int y = __shfl_up(x, s);
            if (lane >= s) x += y;
        }
        if (lane == 63) wsum[w] = x;
        __syncthreads();
        if (w == 0) {
            int ws = (lane < 16) ? wsum[lane] : 0;
#pragma unroll
            for (int s = 1; s < 16; s <<= 1) {
                int y = __shfl_up(ws, s);
                if (lane >= s) ws += y;
            }
            if (lane < 16) wsum[lane] = ws;
        }
        __syncthreads();
        int wbase = (w > 0) ? wsum[w - 1] : 0;
        int incl = x + wbase + carry_s;
        if (i < n) o[i + 1] = incl;
        __syncthreads();
        if (t == 1023) carry_s = incl;
        __syncthreads();
    }
    if (t == 0) o[0] = 0;
}

__global__ __launch_bounds__(256) void fill_k(const int* __restrict__ edges,
                                              const int* __restrict__ off,
                                              int* __restrict__ cur,
                                              int* __restrict__ idx, int n) {
    int i = blockIdx.x * 256 + threadIdx.x;
    if (i < n) {
        int d = edges[n + i];
        int p = atomicAdd(&cur[d], 1);
        idx[off[d] + p] = edges[i];
    }
}

// ---------------------------------------------------------------------------
// nodes [B,M,128] f32 -> node-major bf16 [M,B,128]
// ---------------------------------------------------------------------------
__global__ __launch_bounds__(256) void cast_nodes_k(const float* __restrict__ in,
                                                    __hip_bfloat16* __restrict__ outp) {
    int id = blockIdx.x * 256 + threadIdx.x;  // 2.56M threads, 8 elems each
    int c8 = (id & 15) * 8;
    int b = (id >> 4) & 7;
    int m = id >> 7;
    const float* p = in + ((size_t)b * NM + m) * 128 + c8;
    float4 a = *(const float4*)p;
    float4 b2 = *(const float4*)(p + 4);
    u32 pk0 = f2bf_bits(a.x) | (f2bf_bits(a.y) << 16);
    u32 pk1 = f2bf_bits(a.z) | (f2bf_bits(a.w) << 16);
    u32 pk2 = f2bf_bits(b2.x) | (f2bf_bits(b2.y) << 16);
    u32 pk3 = f2bf_bits(b2.z) | (f2bf_bits(b2.w) << 16);
    *(uint4*)(outp + ((size_t)m * 8 + b) * 128 + c8) = make_uint4(pk0, pk1, pk2, pk3);
}

// ---------------------------------------------------------------------------
// deterministic stat reduction: part[nblk][256] -> pp[64][256] -> sum/sq[128]
// ---------------------------------------------------------------------------
__global__ __launch_bounds__(256) void reduce_part_k(const float* __restrict__ part,
                                                     int nblk, int chunk,
                                                     float* __restrict__ pp) {
    int t = threadIdx.x, j = blockIdx.x;
    int r0 = j * chunk;
    int r1 = min(nblk, r0 + chunk);
    float s = 0.f;
    for (int r = r0; r < r1; ++r) s += part[(size_t)r * 256 + t];
    pp[j * 256 + t] = s;
}

__global__ __launch_bounds__(256) void reduce_final_k(const float* __restrict__ pp,
                                                      float* __restrict__ osum,
                                                      float* __restrict__ osq) {
    int t = threadIdx.x;
    float s = 0.f;
#pragma unroll 8
    for (int j = 0; j < 64; ++j) s += pp[j * 256 + t];
    if (t < 128) osum[t] = s;
    else osq[t - 128] = s;
}

// ---------------------------------------------------------------------------
// weight preps (proven)
// ---------------------------------------------------------------------------
__global__ __launch_bounds__(128) void prep2a_k(const float* __restrict__ ssum,
                                                const float* __restrict__ ssq,
                                                const float* __restrict__ g,
                                                const float* __restrict__ beta,
                                                const float* __restrict__ w_ra2,
                                                const float* __restrict__ b_ra2,
                                                float Nf, float* __restrict__ W2p,
                                                float* __restrict__ b2p) {
    int h = threadIdx.x;
    __shared__ float t1[128];
    float mean = ssum[h] / Nf;
    float var = ssq[h] / Nf - mean * mean;
    float sv = g[h] * rsqrtf(var + BN_EPS);
    t1[h] = beta[h] - mean * sv;
    for (int r = 0; r < 128; ++r) W2p[r * 128 + h] = w_ra2[r * 128 + h] * sv;
    __syncthreads();
    float sb = 0.f;
    for (int d = 0; d < 128; ++d) sb = fmaf(t1[d], w_ra2[h * 128 + d], sb);
    b2p[h] = sb + b_ra2[h];
}

__global__ __launch_bounds__(128) void prep2b_k(const float* __restrict__ w_r2rct,
                                                const float* __restrict__ b_r2rct,
                                                const float* __restrict__ w_r2prd,
                                                const float* __restrict__ b_r2prd,
                                                const float* __restrict__ W2p,
                                                const float* __restrict__ b2p,
                                                float* __restrict__ Wc_r,
                                                float* __restrict__ bc_r,
                                                float* __restrict__ Wc_p,
                                                float* __restrict__ bc_p) {
    int blk = blockIdx.x;
    int d = threadIdx.x;
    int h = blk & 127;
    bool second = blk >= 128;
    const float* w = second ? w_r2prd : w_r2rct;
    const float* bsrc = second ? b_r2prd : b_r2rct;
    float* Wc = second ? Wc_p : Wc_r;
    float* bc = second ? bc_p : bc_r;
    __shared__ float rowv[128];
    __shared__ float red[128];
    rowv[d] = w[h * 128 + d];
    __syncthreads();
    float s = 0.f;
#pragma unroll 4
    for (int j = 0; j < 128; ++j) s = fmaf(rowv[j], W2p[j * 128 + d], s);
    Wc[h * 128 + d] = s;
    red[d] = rowv[d] * b2p[d];
    __syncthreads();
    for (int off = 64; off > 0; off >>= 1) {
        if (d < off) red[d] += red[d + off];
        __syncthreads();
    }
    if (d == 0) bc[h] = red[0] + bsrc[h];
}

// Wt[k][h] = (w_big @ w_src)[h][k&127] (k<128 -> w_s1, else w_s2), k-major;
// bias = [b_big | w_big@b_s1 | w_big@b_s2]
__global__ __launch_bounds__(128) void prep1_k(const float* __restrict__ w_s1,
                                               const float* __restrict__ w_s2,
                                               const float* __restrict__ w_big,
                                               const float* __restrict__ b_s1,
                                               const float* __restrict__ b_s2,
                                               const float* __restrict__ b_big,
                                               float* __restrict__ Wt,
                                               float* __restrict__ bias) {
    int k = blockIdx.x;
    int h = threadIdx.x;
    __shared__ float col[128];
    const float* wsrc = (k < 128) ? w_s1 : w_s2;
    int kk = k & 127;
    col[h] = wsrc[h * 128 + kk];
    __syncthreads();
    float s = 0.f;
#pragma unroll 4
    for (int j = 0; j < 128; ++j) s = fmaf(w_big[h * 128 + j], col[j], s);
    Wt[k * 128 + h] = s;
    if (k == 0) {
        float sb1 = 0.f, sb2 = 0.f;
        for (int j = 0; j < 128; ++j) {
            sb1 = fmaf(w_big[h * 128 + j], b_s1[j], sb1);
            sb2 = fmaf(w_big[h * 128 + j], b_s2[j], sb2);
        }
        bias[h] = b_big[h];
        bias[128 + h] = sb1;
        bias[256 + h] = sb2;
    }
}

__global__ __launch_bounds__(128) void prep3_k(const float* __restrict__ ssum,
                                               const float* __restrict__ ssq,
                                               const float* __restrict__ g,
                                               const float* __restrict__ beta,
                                               const float* __restrict__ w_ma2,
                                               const float* __restrict__ b_ma2,
                                               float Nf, float* __restrict__ WoutT,
                                               float* __restrict__ b_out) {
    int h = threadIdx.x;
    __shared__ float s2[128], t2[128];
    float mean = ssum[h] / Nf;
    float var = ssq[h] / Nf - mean * mean;
    float sv = g[h] * rsqrtf(var + BN_EPS);
    s2[h] = sv;
    t2[h] = beta[h] - mean * sv;
    __syncthreads();
    for (int k = 0; k < 128; ++k) WoutT[k * 128 + h] = w_ma2[h * 128 + k] * s2[k];
    float sb = 0.f;
    for (int k = 0; k < 128; ++k) sb = fmaf(t2[k], w_ma2[h * 128 + k], sb);
    b_out[h] = sb + b_ma2[h];
}

// Repack k-major Wt (K x 128 fp32) to bf16 B-fragment order, nks = K/32
__global__ __launch_bounds__(256) void repack_b_k(const float* __restrict__ Wt,
                                                  short* __restrict__ WtB, int K) {
    int id = blockIdx.x * 256 + threadIdx.x;
    if (id >= K * 128) return;
    int k = id >> 7, h = id & 127;
    int nks = K >> 5;
    int ks = k >> 5, hi = (k >> 3) & 3, j = k & 7;
    int ntile = h >> 4, lc = h & 15;
    int lane = hi * 16 + lc;
    WtB[((ntile * nks + ks) * 64 + lane) * 8 + j] = (short)f2bf_bits(Wt[k * 128 + h]);
}

// ---------------------------------------------------------------------------
// dense MFMA GEMM (GEMM5): Out[n,0:128] = bf16(A[n,0:128]) @ W + bias
// In-place safe (A fully staged to LDS before stores).
// ---------------------------------------------------------------------------
__global__ __launch_bounds__(512, 4) void gemm_dense_mfma(
    const float* A, const short* __restrict__ WtB,
    const float* __restrict__ biasv, float* Out) {
    __shared__ alignas(16) short Asm[64][136];
    const int t = threadIdx.x, n0 = blockIdx.x * 64;
    const int lane = t & 63, w = t >> 6;
    const int lrow = lane & 15, lhi = lane >> 4;

    {
        int row = t >> 3, g8 = t & 7;
        const float* p = A + (size_t)(n0 + row) * 128 + g8 * 16;
        u32* aw = (u32*)&Asm[0][0];
        int wb = row * 68 + g8 * 8;
#pragma unroll
        for (int c = 0; c < 2; ++c) {
            float4 a = *(const float4*)(p + c * 8);
            float4 b2 = *(const float4*)(p + c * 8 + 4);
            u32 pk0 = f2bf_bits(a.x) | (f2bf_bits(a.y) << 16);
            u32 pk1 = f2bf_bits(a.z) | (f2bf_bits(a.w) << 16);
            u32 pk2 = f2bf_bits(b2.x) | (f2bf_bits(b2.y) << 16);
            u32 pk3 = f2bf_bits(b2.z) | (f2bf_bits(b2.w) << 16);
            *(uint4*)&aw[wb + c * 4] = make_uint4(pk0, pk1, pk2, pk3);
        }
    }
    short8 bfrag[4];
#pragma unroll
    for (int ks = 0; ks < 4; ++ks)
        bfrag[ks] = *(const short8*)(WtB + (size_t)((w * 4 + ks) * 64 + lane) * 8);
    __syncthreads();

    f32x4 acc[4];
#pragma unroll
    for (int rt = 0; rt < 4; ++rt) acc[rt] = (f32x4){0.f, 0.f, 0.f, 0.f};
#pragma unroll
    for (int rt = 0; rt < 4; ++rt)
#pragma unroll
        for (int ks = 0; ks < 4; ++ks) {
            short8 af = *(const short8*)&Asm[rt * 16 + lrow][ks * 32 + lhi * 8];
            acc[rt] = MFMA16(af, bfrag[ks], acc[rt]);
        }
    int col = w * 16 + lrow;
    float bb = biasv[col];
#pragma unroll
    for (int rt = 0; rt < 4; ++rt)
#pragma unroll
        for (int i = 0; i < 4; ++i) {
            int row = rt * 16 + lhi * 4 + i;
            Out[(size_t)(n0 + row) * 128 + col] = acc[rt][i] + bb;
        }
}

// ---------------------------------------------------------------------------
// MFMA gather GEMM, node-major src [nsrc, B=8, 128] bf16.
// Block = 8 bins x 8 batches = 64 rows; wave w owns bin (blockIdx*8+w);
// lane: batch = lane>>3, ck = lane&7 (16 cols). Per edge the wave reads one
// fully contiguous 2KB burst. A[:,0:128] = mean over CSR1[bin] of src rows;
// A[:,128:256] = mean over CSR2[bin]. Out = relu(A@W + base + m1*bm1+m2*bm2).
// Per-block BN partial stats -> part[blk][256] (deterministic reduce later).
// PERM: write Out row (batch*permN + bin) (un-permute to batch-major).
// ---------------------------------------------------------------------------
template <typename OT, bool PERM>
__global__ __launch_bounds__(512, 4) void gemm_gather_mfma(
    const __hip_bfloat16* __restrict__ src,
    const int* __restrict__ off1, const int* __restrict__ idx1,
    const int* __restrict__ off2, const int* __restrict__ idx2,
    const short* __restrict__ WtB, const float* __restrict__ biasv,
    OT* __restrict__ Out, int permN, float* __restrict__ part) {
    __shared__ alignas(16) short Asm[64][264];
    __shared__ float m1s[64], m2s[64];
    const int t = threadIdx.x;
    const int lane = t & 63;
    const int w = __builtin_amdgcn_readfirstlane(t >> 6);
    const int lrow = lane & 15, lhi = lane >> 4;
    const int bin0 = blockIdx.x * 8;

    // B fragments early (in flight during gather)
    short8 bfrag[8];
#pragma unroll
    for (int ks = 0; ks < 8; ++ks)
        bfrag[ks] = *(const short8*)(WtB + (size_t)((w * 8 + ks) * 64 + lane) * 8);

    // ---- gather ----
    {
        const int rb = bin0 + w;
        const int batch = lane >> 3, ck = lane & 7;
        const int arow = w * 8 + batch;
        const __hip_bfloat16* lsrc = src + batch * 128 + ck * 16;
#pragma unroll
        for (int half = 0; half < 2; ++half) {
            const int* offp = half ? off2 : off1;
            const int* idxp = half ? idx2 : idx1;
            int e0 = offp[rb], e1 = offp[rb + 1];
            float g[16];
#pragma unroll
            for (int j = 0; j < 16; ++j) g[j] = 0.f;
            int e = e0;
            for (; e + 2 <= e1; e += 2) {
                int i0 = idxp[e], i1 = idxp[e + 1];
                acc16(lsrc + (size_t)i0 * 1024, g);
                acc16(lsrc + (size_t)i1 * 1024, g);
            }
            if (e < e1) acc16(lsrc + (size_t)idxp[e] * 1024, g);
            int cnt = e1 - e0;
            float sc = (cnt > 0) ? 1.f / (float)cnt : 0.f;
            if (ck == 0) (half ? m2s : m1s)[arow] = (cnt > 0) ? 1.f : 0.f;
            u32* aw = (u32*)&Asm[0][0];
            int wb = arow * 132 + half * 64 + ck * 8;
            u32 pk[8];
#pragma unroll
            for (int q = 0; q < 8; ++q)
                pk[q] = f2bf_bits(g[q * 2] * sc) | (f2bf_bits(g[q * 2 + 1] * sc) << 16);
            *(uint4*)&aw[wb] = make_uint4(pk[0], pk[1], pk[2], pk[3]);
            *(uint4*)&aw[wb + 4] = make_uint4(pk[4], pk[5], pk[6], pk[7]);
        }
    }
    __syncthreads();

    // ---- MFMA: 4 row-tiles x 8 k-steps; wave w -> col-tile w ----
    f32x4 acc[4];
#pragma unroll
    for (int rt = 0; rt < 4; ++rt) acc[rt] = (f32x4){0.f, 0.f, 0.f, 0.f};
#pragma unroll
    for (int rt = 0; rt < 4; ++rt)
#pragma unroll
        for (int ks = 0; ks < 8; ++ks) {
            short8 af = *(const short8*)&Asm[rt * 16 + lrow][ks * 32 + lhi * 8];
            acc[rt] = MFMA16(af, bfrag[ks], acc[rt]);
        }

    // ---- epilogue ----
    const int col = w * 16 + lrow;
    float bb = biasv[col], bm1 = biasv[128 + col], bm2 = biasv[256 + col];
    float ps = 0.f, pq = 0.f;
#pragma unroll
    for (int rt = 0; rt < 4; ++rt)
#pragma unroll
        for (int i = 0; i < 4; ++i) {
            int row = rt * 16 + lhi * 4 + i;
            float v = acc[rt][i] + bb + m1s[row] * bm1 + m2s[row] * bm2;
            v = fmaxf(v, 0.f);
            ps += v;
            pq += v * v;
            size_t orow = PERM ? ((size_t)(row & 7) * permN + (bin0 + (row >> 3)))
                               : (size_t)(blockIdx.x * 64 + row);
            storev(&Out[orow * 128 + col], v);
        }
    ps += __shfl_xor(ps, 16);
    ps += __shfl_xor(ps, 32);
    pq += __shfl_xor(pq, 16);
    pq += __shfl_xor(pq, 32);
    if (lhi == 0) {
        part[(size_t)blockIdx.x * 256 + col] = ps;
        part[(size_t)blockIdx.x * 256 + 128 + col] = pq;
    }
}

// ---------------------------------------------------------------------------
// launch
// ---------------------------------------------------------------------------
extern "C" void kernel_launch(void* const* d_in, const int* in_sizes, int n_in,
                              void* d_out, int out_size, void* d_ws, size_t ws_size,
                              hipStream_t stream) {
    const float* nodes = (const float*)d_in[0];
    const int* r2e = (const int*)d_in[1];
    const int* p2e = (const int*)d_in[2];
    const int* e2r = (const int*)d_in[3];
    const int* e2p = (const int*)d_in[4];
    const float* w_rct = (const float*)d_in[5];
    const float* b_rct = (const float*)d_in[6];
    const float* w_prd = (const float*)d_in[7];
    const float* b_prd = (const float*)d_in[8];
    const float* w_ra1 = (const float*)d_in[9];
    const float* b_ra1 = (const float*)d_in[10];
    const float* bn_r_g = (const float*)d_in[11];
    const float* bn_r_b = (const float*)d_in[12];
    const float* w_ra2 = (const float*)d_in[13];
    const float* b_ra2 = (const float*)d_in[14];
    const float* w_r2rct = (const float*)d_in[15];
    const float* b_r2rct = (const float*)d_in[16];
    const float* w_r2prd = (const float*)d_in[17];
    const float* b_r2prd = (const float*)d_in[18];
    const float* w_ma1 = (const float*)d_in[19];
    const float* b_ma1 = (const float*)d_in[20];
    const float* bn_m_g = (const float*)d_in[21];
    const float* bn_m_b = (const float*)d_in[22];
    const float* w_ma2 = (const float*)d_in[23];
    const float* b_ma2 = (const float*)d_in[24];

    char* ws = (char*)d_ws;
    size_t off = 0;
    auto alloc = [&](size_t bytes) -> char* {
        off = (off + 255) & ~(size_t)255;
        char* p = ws + off;
        off += bytes;
        return p;
    };

    const size_t H1B = (size_t)NR * NB * 128 * 2;  // 102.4 MB node-major [R,B,128]
    __hip_bfloat16* h1 = (__hip_bfloat16*)alloc(H1B);

    char* cntcur = alloc((size_t)8 * (NR + NR + NM + NM));
    int* cnt_r = (int*)cntcur;
    int* cnt_p = cnt_r + NR;
    int* cnt_er = cnt_p + NR;
    int* cnt_ep = cnt_er + NM;
    int* cur_r = cnt_ep + NM;
    int* cur_p = cur_r + NR;
    int* cur_er = cur_p + NR;
    int* cur_ep = cur_er + NM;
    int* off_r = (int*)alloc((NR + 1) * 4);
    int* off_p = (int*)alloc((NR + 1) * 4);
    int* off_er = (int*)alloc((NM + 1) * 4);
    int* off_ep = (int*)alloc((NM + 1) * 4);
    int* idx_r = (int*)alloc(NE * 4);
    int* idx_p = (int*)alloc(NE * 4);
    int* idx_er = (int*)alloc(NE * 4);
    int* idx_ep = (int*)alloc(NE * 4);

    float* statblk = (float*)alloc(4 * 128 * 4);
    float* sum1 = statblk;
    float* sq1 = statblk + 128;
    float* sum2 = statblk + 256;
    float* sq2 = statblk + 384;
    float* Wt1 = (float*)alloc(256 * 128 * 4);
    float* bias1 = (float*)alloc(3 * 128 * 4);
    float* W2p = (float*)alloc(128 * 128 * 4);
    float* b2p = (float*)alloc(128 * 4);
    float* Wc_r = (float*)alloc(128 * 128 * 4);
    float* bc_r = (float*)alloc(128 * 4);
    float* Wc_p = (float*)alloc(128 * 128 * 4);
    float* bc_p = (float*)alloc(128 * 4);
    float* Wt2 = (float*)alloc(256 * 128 * 4);
    float* bias2 = (float*)alloc(3 * 128 * 4);
    float* WoutT = (float*)alloc(128 * 128 * 4);
    float* b_out = (float*)alloc(128 * 4);
    short* WtB1 = (short*)alloc(256 * 128 * 2);
    short* WtB2 = (short*)alloc(256 * 128 * 2);
    short* WtBo = (short*)alloc(128 * 128 * 2);
    const int NBLK1 = NR / 8;  // 6250
    const int NBLK2 = NM / 8;  // 2500
    float* part1 = (float*)alloc((size_t)NBLK1 * 256 * 4);
    float* part2 = (float*)alloc((size_t)NBLK2 * 256 * 4);
    float* pp1 = (float*)alloc(64 * 256 * 4);
    float* pp2 = (float*)alloc(64 * 256 * 4);
    (void)ws_size;

    // nb16 [M,B,128] bf16 (41 MB) lives in d_out; later overwritten by h2
    __hip_bfloat16* nb16 = (__hip_bfloat16*)d_out;
    float* h2 = (float*)d_out;

    hipMemsetAsync(cntcur, 0, (size_t)8 * (NR + NR + NM + NM), stream);

    // ---- CSR build ----
    const int EB = (NE + 255) / 256;
    hist_k<<<EB, 256, 0, stream>>>(r2e + NE, cnt_r, NE);
    hist_k<<<EB, 256, 0, stream>>>(p2e + NE, cnt_p, NE);
    hist_k<<<EB, 256, 0, stream>>>(e2r + NE, cnt_er, NE);
    hist_k<<<EB, 256, 0, stream>>>(e2p + NE, cnt_ep, NE);
    scan4_k<<<4, 1024, 0, stream>>>(cnt_r, off_r, NR, cnt_p, off_p, NR,
                                    cnt_er, off_er, NM, cnt_ep, off_ep, NM);
    fill_k<<<EB, 256, 0, stream>>>(r2e, off_r, cur_r, idx_r, NE);
    fill_k<<<EB, 256, 0, stream>>>(p2e, off_p, cur_p, idx_p, NE);
    fill_k<<<EB, 256, 0, stream>>>(e2r, off_er, cur_er, idx_er, NE);
    fill_k<<<EB, 256, 0, stream>>>(e2p, off_ep, cur_ep, idx_ep, NE);

    // ---- cast nodes -> node-major bf16 (GEMM1 folded into gather weights) ----
    cast_nodes_k<<<(NB * NM * 128 / 8) / 256, 256, 0, stream>>>(nodes, nb16);

    // ---- GEMM2 (gather): h1 = relu(gather(nb16)@[w_ra1@w_rct ; w_ra1@w_prd]) ----
    prep1_k<<<256, 128, 0, stream>>>(w_rct, w_prd, w_ra1, b_rct, b_prd, b_ra1, Wt1, bias1);
    repack_b_k<<<128, 256, 0, stream>>>(Wt1, WtB1, 256);
    gemm_gather_mfma<__hip_bfloat16, false><<<NBLK1, 512, 0, stream>>>(
        nb16, off_r, idx_r, off_p, idx_p, WtB1, bias1, h1, 0, part1);
    reduce_part_k<<<64, 256, 0, stream>>>(part1, NBLK1, (NBLK1 + 63) / 64, pp1);
    reduce_final_k<<<1, 256, 0, stream>>>(pp1, sum1, sq1);

    // ---- fold BN1 -> w_ra2 -> w_r2rct/w_r2prd -> w_ma1 ----
    prep2a_k<<<1, 128, 0, stream>>>(sum1, sq1, bn_r_g, bn_r_b, w_ra2, b_ra2,
                                    (float)((size_t)NB * NR), W2p, b2p);
    prep2b_k<<<256, 128, 0, stream>>>(w_r2rct, b_r2rct, w_r2prd, b_r2prd, W2p, b2p,
                                      Wc_r, bc_r, Wc_p, bc_p);
    prep1_k<<<256, 128, 0, stream>>>(Wc_r, Wc_p, w_ma1, bc_r, bc_p, b_ma1, Wt2, bias2);
    repack_b_k<<<128, 256, 0, stream>>>(Wt2, WtB2, 256);

    // ---- GEMM4 (gather): h2[b,m,:] = relu(gather(h1)@Wt2 + biases) -> d_out ----
    gemm_gather_mfma<float, true><<<NBLK2, 512, 0, stream>>>(
        h1, off_er, idx_er, off_ep, idx_ep, WtB2, bias2, h2, NM, part2);
    reduce_part_k<<<64, 256, 0, stream>>>(part2, NBLK2, (NBLK2 + 63) / 64, pp2);
    reduce_final_k<<<1, 256, 0, stream>>>(pp2, sum2, sq2);

    // ---- fold BN2; GEMM5 (MFMA) in-place on d_out ----
    prep3_k<<<1, 128, 0, stream>>>(sum2, sq2, bn_m_g, bn_m_b, w_ma2, b_ma2,
                                   (float)((size_t)NB * NM), WoutT, b_out);
    repack_b_k<<<64, 256, 0, stream>>>(WoutT, WtBo, 128);
    gemm_dense_mfma<<<(NB * NM) / 64, 512, 0, stream>>>(h2, WtBo, b_out, (float*)d_out);
}